// Round 1
// baseline (590.440 us; speedup 1.0000x reference)
//
#include <hip/hip_runtime.h>
#include <math.h>

#define B_ 2
#define T_ 2048
#define D_ 2048
#define H_ 16
#define M_ 4096          // B*T
#define TD_ (T_ * D_)
#define EPS_ 1e-5f

#define BM 128
#define BN 128
#define BK 64

typedef __bf16 bf16x8 __attribute__((ext_vector_type(8)));
typedef float f32x4 __attribute__((ext_vector_type(4)));

__device__ __forceinline__ float sigm(float z) { return 1.f / (1.f + __expf(-z)); }

__device__ __forceinline__ ushort f2bf(float f) {  // RNE f32 -> bf16 bits
    union { float f; uint u; } x; x.f = f;
    uint r = x.u + 0x7fffu + ((x.u >> 16) & 1u);
    return (ushort)(r >> 16);
}
__device__ __forceinline__ float bflo(uint u) { union { uint u; float f; } x; x.u = u << 16; return x.f; }
__device__ __forceinline__ float bfhi(uint u) { union { uint u; float f; } x; x.u = u & 0xffff0000u; return x.f; }

__device__ __forceinline__ void gload_lds16(const void* g, void* l) {
    __builtin_amdgcn_global_load_lds((const __attribute__((address_space(1))) void*)g,
                                     (__attribute__((address_space(3))) void*)l, 16, 0, 0);
}

// ---------- weights f32 -> bf16 (order: Wq,Wk,Wv,Wig,Wog,Wo) ----------
__global__ __launch_bounds__(256) void cvtw_kernel(
    const float* __restrict__ Wq, const float* __restrict__ Wk, const float* __restrict__ Wv,
    const float* __restrict__ Wig, const float* __restrict__ Wog, const float* __restrict__ Wo,
    ushort* __restrict__ W6)
{
    const int z = blockIdx.y;
    const float* src = z == 0 ? Wq : z == 1 ? Wk : z == 2 ? Wv : z == 3 ? Wig : z == 4 ? Wog : Wo;
    const int i4 = (blockIdx.x * 256 + threadIdx.x) * 4;
    float4 f = *(const float4*)(src + i4);
    ushort4 o; o.x = f2bf(f.x); o.y = f2bf(f.y); o.z = f2bf(f.z); o.w = f2bf(f.w);
    *(ushort4*)(W6 + (size_t)z * ((size_t)D_ * D_) + i4) = o;
}

// ---------- causal depthwise conv (K=4) + silu; also emits x as bf16 ----------
__global__ __launch_bounds__(256) void conv_kernel(
    const float* __restrict__ x, const float* __restrict__ cw, const float* __restrict__ cb,
    ushort* __restrict__ xb, ushort* __restrict__ xcb)
{
    const int idx = blockIdx.x * 256 + threadIdx.x;
    const int c = idx & (D_ - 1);
    const int t = (idx >> 11) & (T_ - 1);
    const float* w = cw + c * 4;
    const float x3 = x[idx];
    float a = cb[c] + w[3] * x3;
    if (t >= 1) a += w[2] * x[idx - D_];
    if (t >= 2) a += w[1] * x[idx - 2 * D_];
    if (t >= 3) a += w[0] * x[idx - 3 * D_];
    xb[idx] = f2bf(x3);
    xcb[idx] = f2bf(a * sigm(a));
}

// ---------- GEMM: C[M,N] = A[M,K] * W[N,K]^T  (both bf16, K-major) ----------
template <bool BF16OUT>
__device__ __forceinline__ void gemm_body(
    const ushort* __restrict__ A, const ushort* __restrict__ Bw,
    ushort* __restrict__ Cb, float* __restrict__ Cf)
{
    __shared__ __bf16 As[BM][BK];
    __shared__ __bf16 Bs[BN][BK];
    const int tid = threadIdx.x;
    const int lane = tid & 63;
    const int wid = tid >> 6;
    const int wr = wid >> 1, wc = wid & 1;     // 2x2 wave grid, 64x64 per wave
    const int brow = blockIdx.y * BM;
    const int bcol = blockIdx.x * BN;
    const int lrow = lane & 15;
    const int lko = (lane >> 4) * 8;

    f32x4 acc[4][4] = {};

    const int offb = wid * 1024 + lane * 16;   // per-thread first chunk byte offset
    for (int k0 = 0; k0 < D_; k0 += BK) {
        #pragma unroll
        for (int i = 0; i < 4; ++i) {
            const int off = offb + i * 4096;
            const int row = off >> 7;          // 128 B per LDS row (BK*2)
            const int ce = (off & 127) >> 1;   // element offset within row
            gload_lds16(A  + (size_t)(brow + row) * D_ + (k0 + ce), (char*)(&As[0][0]) + off);
            gload_lds16(Bw + (size_t)(bcol + row) * D_ + (k0 + ce), (char*)(&Bs[0][0]) + off);
        }
        __syncthreads();
        #pragma unroll
        for (int kk = 0; kk < 2; ++kk) {
            bf16x8 av[4], bv[4];
            #pragma unroll
            for (int m = 0; m < 4; ++m)
                av[m] = *(const bf16x8*)(&As[wr * 64 + m * 16 + lrow][kk * 32 + lko]);
            #pragma unroll
            for (int n = 0; n < 4; ++n)
                bv[n] = *(const bf16x8*)(&Bs[wc * 64 + n * 16 + lrow][kk * 32 + lko]);
            #pragma unroll
            for (int m = 0; m < 4; ++m)
                #pragma unroll
                for (int n = 0; n < 4; ++n)
                    acc[m][n] = __builtin_amdgcn_mfma_f32_16x16x32_bf16(av[m], bv[n], acc[m][n], 0, 0, 0);
        }
        __syncthreads();
    }

    const int r0 = (lane >> 4) * 4;            // C/D: col=lane&15, row=(lane>>4)*4+r
    #pragma unroll
    for (int m = 0; m < 4; ++m)
      #pragma unroll
      for (int n = 0; n < 4; ++n) {
        const int row = brow + wr * 64 + m * 16 + r0;
        const int col = bcol + wc * 64 + n * 16 + lrow;
        #pragma unroll
        for (int r = 0; r < 4; ++r) {
            if (BF16OUT) Cb[(size_t)(row + r) * D_ + col] = f2bf(acc[m][n][r]);
            else         Cf[(size_t)(row + r) * D_ + col] = acc[m][n][r];
        }
      }
}

__global__ __launch_bounds__(256) void gemm5_kernel(
    const ushort* __restrict__ xb, const ushort* __restrict__ xcb,
    const ushort* __restrict__ W6, ushort* __restrict__ Obuf)
{
    const int z = blockIdx.z;                  // 0:q 1:k 2:v 3:ig 4:og
    const ushort* A = (z < 3) ? xb : xcb;
    gemm_body<true>(A, W6 + (size_t)z * ((size_t)D_ * D_),
                    Obuf + (size_t)z * ((size_t)M_ * D_), nullptr);
}

__global__ __launch_bounds__(256) void gemm_out_kernel(
    const ushort* __restrict__ gated, const ushort* __restrict__ W6, float* __restrict__ out)
{
    gemm_body<false>(gated, W6 + (size_t)5 * ((size_t)D_ * D_), nullptr, out);
}

// ---------- gamma = sigmoid(x_conv . Wg[h] + b_g[h]) ----------
__global__ __launch_bounds__(256) void gamma_kernel(
    const ushort* __restrict__ xcb, const float* __restrict__ Wg,
    const float* __restrict__ bg, float* __restrict__ gamma)
{
    const int gid = blockIdx.x * 256 + threadIdx.x;   // (b*T+t)*16 + h
    const int h = gid & (H_ - 1);
    const int token = gid >> 4;
    const ushort* xr = xcb + (size_t)token * D_;
    const float* wr = Wg + (size_t)h * D_;
    float acc = 0.f;
    for (int i = 0; i < D_; i += 8) {
        uint4 u = *(const uint4*)(xr + i);
        float4 w0 = *(const float4*)(wr + i);
        float4 w1 = *(const float4*)(wr + i + 4);
        acc += bflo(u.x) * w0.x + bfhi(u.x) * w0.y + bflo(u.y) * w0.z + bfhi(u.y) * w0.w;
        acc += bflo(u.z) * w1.x + bfhi(u.z) * w1.y + bflo(u.w) * w1.z + bfhi(u.w) * w1.w;
    }
    gamma[gid] = sigm(acc + bg[h]);
}

// ---------- bterm = sigmoid(igp + b_ig) * l2norm(k) * v ----------
__global__ __launch_bounds__(256) void bterm_kernel(
    const ushort* __restrict__ kb, const ushort* __restrict__ vb,
    const ushort* __restrict__ igb, const float* __restrict__ big,
    float* __restrict__ bt)
{
    const int token = blockIdx.x;
    const int tid = threadIdx.x;              // 16 threads per head (8 elems each)
    const int c0 = tid * 8;
    const size_t base = (size_t)token * D_ + c0;
    uint4 ku = *(const uint4*)(kb + base);
    uint4 vu = *(const uint4*)(vb + base);
    uint4 iu = *(const uint4*)(igb + base);
    float kf[8] = { bflo(ku.x), bfhi(ku.x), bflo(ku.y), bfhi(ku.y),
                    bflo(ku.z), bfhi(ku.z), bflo(ku.w), bfhi(ku.w) };
    float vf[8] = { bflo(vu.x), bfhi(vu.x), bflo(vu.y), bfhi(vu.y),
                    bflo(vu.z), bfhi(vu.z), bflo(vu.w), bfhi(vu.w) };
    float gf[8] = { bflo(iu.x), bfhi(iu.x), bflo(iu.y), bfhi(iu.y),
                    bflo(iu.z), bfhi(iu.z), bflo(iu.w), bfhi(iu.w) };
    float ss = 0.f;
    #pragma unroll
    for (int j = 0; j < 8; ++j) ss += kf[j] * kf[j];
    #pragma unroll
    for (int o = 1; o < 16; o <<= 1) ss += __shfl_xor(ss, o);
    const float sc = 1.f / fmaxf(sqrtf(ss), 1e-12f);
    float ot[8];
    #pragma unroll
    for (int j = 0; j < 8; ++j)
        ot[j] = sigm(gf[j] + big[c0 + j]) * (kf[j] * sc) * vf[j];
    float4 o0 = { ot[0], ot[1], ot[2], ot[3] };
    float4 o1 = { ot[4], ot[5], ot[6], ot[7] };
    *(float4*)(bt + base) = o0;
    *(float4*)(bt + base + 4) = o1;
}

// ---------- sequential scan: mem[t] = gamma[t]*mem[t-1] + b[t], in-place ----------
__global__ __launch_bounds__(64) void scan_kernel(
    float* __restrict__ mem, const float* __restrict__ gamma)
{
    const int chain = blockIdx.x * 64 + threadIdx.x;  // b*2048 + c
    const int b = chain >> 11;
    const int c = chain & (D_ - 1);
    const int h = c >> 7;
    float* p = mem + (size_t)b * TD_ + c;
    const float* g = gamma + (size_t)b * (T_ * H_) + h;
    float m = 0.f;
    #pragma unroll 8
    for (int t = 0; t < T_; ++t) {
        const float btv = p[(size_t)t * D_];
        const float gt = g[(size_t)t * H_];
        m = fmaf(gt, m, btv);
        p[(size_t)t * D_] = m;
    }
}

// ---------- GN(mem)*l2norm(q) -> GN -> *sigmoid(og) -> bf16; also rnn_state ----------
__global__ __launch_bounds__(256) void norm_kernel(
    const float* __restrict__ mem, const ushort* __restrict__ qb,
    const ushort* __restrict__ ogb, const float* __restrict__ bog,
    const float* __restrict__ mnw, const float* __restrict__ mnb,
    const float* __restrict__ gnw, const float* __restrict__ gnb,
    ushort* __restrict__ gated, float* __restrict__ rnn)
{
    const int token = blockIdx.x;
    const int tid = threadIdx.x;
    const int c0 = tid * 8;
    const size_t base = (size_t)token * D_ + c0;
    float mm[8];
    { float4 a = *(const float4*)(mem + base); float4 b2 = *(const float4*)(mem + base + 4);
      mm[0]=a.x; mm[1]=a.y; mm[2]=a.z; mm[3]=a.w; mm[4]=b2.x; mm[5]=b2.y; mm[6]=b2.z; mm[7]=b2.w; }
    float s1 = 0.f, s2 = 0.f;
    #pragma unroll
    for (int j = 0; j < 8; ++j) { s1 += mm[j]; s2 += mm[j] * mm[j]; }
    #pragma unroll
    for (int o = 1; o < 16; o <<= 1) { s1 += __shfl_xor(s1, o); s2 += __shfl_xor(s2, o); }
    const float mu = s1 * (1.f / 128.f);
    const float inv = 1.f / sqrtf(fmaxf(s2 * (1.f / 128.f) - mu * mu, 0.f) + EPS_);
    uint4 qu = *(const uint4*)(qb + base);
    float qf[8] = { bflo(qu.x), bfhi(qu.x), bflo(qu.y), bfhi(qu.y),
                    bflo(qu.z), bfhi(qu.z), bflo(qu.w), bfhi(qu.w) };
    float qs = 0.f;
    #pragma unroll
    for (int j = 0; j < 8; ++j) qs += qf[j] * qf[j];
    #pragma unroll
    for (int o = 1; o < 16; o <<= 1) qs += __shfl_xor(qs, o);
    const float qsc = 1.f / fmaxf(sqrtf(qs), 1e-12f);
    float ov[8]; float t1 = 0.f, t2 = 0.f;
    #pragma unroll
    for (int j = 0; j < 8; ++j) {
        const float mn = (mm[j] - mu) * inv * mnw[c0 + j] + mnb[c0 + j];
        ov[j] = mn * (qf[j] * qsc);
        t1 += ov[j]; t2 += ov[j] * ov[j];
    }
    #pragma unroll
    for (int o = 1; o < 16; o <<= 1) { t1 += __shfl_xor(t1, o); t2 += __shfl_xor(t2, o); }
    const float mu2 = t1 * (1.f / 128.f);
    const float inv2 = 1.f / sqrtf(fmaxf(t2 * (1.f / 128.f) - mu2 * mu2, 0.f) + EPS_);
    uint4 ou = *(const uint4*)(ogb + base);
    float of[8] = { bflo(ou.x), bfhi(ou.x), bflo(ou.y), bfhi(ou.y),
                    bflo(ou.z), bfhi(ou.z), bflo(ou.w), bfhi(ou.w) };
    uint pk[4];
    #pragma unroll
    for (int j2 = 0; j2 < 4; ++j2) {
        const int e0 = 2 * j2, e1 = 2 * j2 + 1;
        float g0 = ((ov[e0] - mu2) * inv2 * gnw[c0 + e0] + gnb[c0 + e0]) * sigm(of[e0] + bog[c0 + e0]);
        float g1 = ((ov[e1] - mu2) * inv2 * gnw[c0 + e1] + gnb[c0 + e1]) * sigm(of[e1] + bog[c0 + e1]);
        pk[j2] = (uint)f2bf(g0) | ((uint)f2bf(g1) << 16);
    }
    uint4 st = { pk[0], pk[1], pk[2], pk[3] };
    *(uint4*)(gated + base) = st;
    if ((token & (T_ - 1)) == T_ - 1) {       // t == T-1: raw mem -> next_rnn_state
        float* r = rnn + (size_t)(token >> 11) * D_ + c0;
        float4 r0 = { mm[0], mm[1], mm[2], mm[3] };
        float4 r1 = { mm[4], mm[5], mm[6], mm[7] };
        *(float4*)r = r0; *(float4*)(r + 4) = r1;
    }
}

// ---------- conv cache: x^T last K-1 timesteps ----------
__global__ __launch_bounds__(256) void cache_kernel(const float* __restrict__ x, float* __restrict__ out)
{
    const int idx = blockIdx.x * 256 + threadIdx.x;  // B*D*3
    if (idx >= B_ * D_ * 3) return;
    const int b = idx / (D_ * 3);
    const int rem = idx - b * (D_ * 3);
    const int c = rem / 3;
    const int j = rem - c * 3;
    out[idx] = x[((size_t)b * T_ + (T_ - 3 + j)) * D_ + c];
}

extern "C" void kernel_launch(void* const* d_in, const int* in_sizes, int n_in,
                              void* d_out, int out_size, void* d_ws, size_t ws_size,
                              hipStream_t stream)
{
    const float* x   = (const float*)d_in[0];
    const float* Wq  = (const float*)d_in[1];
    const float* Wk  = (const float*)d_in[2];
    const float* Wv  = (const float*)d_in[3];
    const float* Wo  = (const float*)d_in[4];
    const float* cw  = (const float*)d_in[5];
    const float* cb  = (const float*)d_in[6];
    const float* Wig = (const float*)d_in[7];
    const float* big = (const float*)d_in[8];
    const float* Wog = (const float*)d_in[9];
    const float* bog = (const float*)d_in[10];
    const float* Wg  = (const float*)d_in[11];
    const float* bg  = (const float*)d_in[12];
    const float* gnw = (const float*)d_in[13];
    const float* gnb = (const float*)d_in[14];
    const float* mnw = (const float*)d_in[15];
    const float* mnb = (const float*)d_in[16];

    char* ws = (char*)d_ws;
    ushort* W6   = (ushort*)ws;                                         // 50,331,648 B
    ushort* xb   = (ushort*)(ws + 50331648);                            // 16,777,216
    ushort* xcb  = (ushort*)(ws + 50331648 + 16777216);                 // 16,777,216
    ushort* Obuf = (ushort*)(ws + 50331648 + 2 * 16777216);             // 5 x 16,777,216
    float*  gam  = (float*)(ws + 50331648 + 7 * 16777216);              // 262,144
    float*  bt   = (float*)(ws + 50331648 + 7 * 16777216 + 262144);     // 33,554,432

    ushort* q    = Obuf;
    ushort* k    = Obuf + (size_t)M_ * D_;
    ushort* v    = Obuf + 2 * (size_t)M_ * D_;
    ushort* igp  = Obuf + 3 * (size_t)M_ * D_;
    ushort* ogp  = Obuf + 4 * (size_t)M_ * D_;
    ushort* gated = k;  // k is dead after bterm_kernel

    float* out  = (float*)d_out;
    float* rnn  = out + (size_t)M_ * D_;
    float* cach = rnn + B_ * D_;

    cvtw_kernel<<<dim3(4096, 6), 256, 0, stream>>>(Wq, Wk, Wv, Wig, Wog, Wo, W6);
    conv_kernel<<<dim3(M_ * D_ / 256), 256, 0, stream>>>(x, cw, cb, xb, xcb);
    gemm5_kernel<<<dim3(D_ / BN, M_ / BM, 5), 256, 0, stream>>>(xb, xcb, W6, Obuf);
    gamma_kernel<<<dim3(M_ * H_ / 256), 256, 0, stream>>>(xcb, Wg, bg, gam);
    bterm_kernel<<<dim3(M_), 256, 0, stream>>>(k, v, igp, big, bt);
    scan_kernel<<<dim3(64), 64, 0, stream>>>(bt, gam);
    norm_kernel<<<dim3(M_), 256, 0, stream>>>(bt, q, ogp, bog, mnw, mnb, gnw, gnb, gated, rnn);
    gemm_out_kernel<<<dim3(D_ / BN, M_ / BM), 256, 0, stream>>>(gated, W6, out);
    cache_kernel<<<dim3(48), 256, 0, stream>>>(x, cach);
}

// Round 2
// 461.638 us; speedup vs baseline: 1.2790x; 1.2790x over previous
//
#include <hip/hip_runtime.h>
#include <math.h>

#define B_ 2
#define T_ 2048
#define D_ 2048
#define H_ 16
#define M_ 4096          // B*T
#define TD_ (T_ * D_)
#define EPS_ 1e-5f
#define NC_ 32           // scan chunks
#define CL_ 64           // scan chunk length

typedef __bf16 bf16x8 __attribute__((ext_vector_type(8)));
typedef float f32x4 __attribute__((ext_vector_type(4)));

__device__ __forceinline__ float sigm(float z) { return 1.f / (1.f + __expf(-z)); }

__device__ __forceinline__ ushort f2bf(float f) {  // RNE f32 -> bf16 bits
    union { float f; uint u; } x; x.f = f;
    uint r = x.u + 0x7fffu + ((x.u >> 16) & 1u);
    return (ushort)(r >> 16);
}
__device__ __forceinline__ float bflo(uint u) { union { uint u; float f; } x; x.u = u << 16; return x.f; }
__device__ __forceinline__ float bfhi(uint u) { union { uint u; float f; } x; x.u = u & 0xffff0000u; return x.f; }

__device__ __forceinline__ void gload_lds16(const void* g, void* l) {
    __builtin_amdgcn_global_load_lds((const __attribute__((address_space(1))) void*)g,
                                     (__attribute__((address_space(3))) void*)l, 16, 0, 0);
}

template <int IMM>
__device__ __forceinline__ bf16x8 dsr(uint addr) {
    int4 d;
    asm volatile("ds_read_b128 %0, %1 offset:%2" : "=v"(d) : "v"(addr), "n"(IMM));
    return __builtin_bit_cast(bf16x8, d);
}
#define LGKM0 do { asm volatile("s_waitcnt lgkmcnt(0)" ::: "memory"); __builtin_amdgcn_sched_barrier(0); } while (0)
#define SBAR  __builtin_amdgcn_s_barrier()

// ---------- weights f32 -> bf16 (order: Wq,Wk,Wv,Wig,Wog,Wo) ----------
__global__ __launch_bounds__(256) void cvtw_kernel(
    const float* __restrict__ Wq, const float* __restrict__ Wk, const float* __restrict__ Wv,
    const float* __restrict__ Wig, const float* __restrict__ Wog, const float* __restrict__ Wo,
    ushort* __restrict__ W6)
{
    const int z = blockIdx.y;
    const float* src = z == 0 ? Wq : z == 1 ? Wk : z == 2 ? Wv : z == 3 ? Wig : z == 4 ? Wog : Wo;
    const int i4 = (blockIdx.x * 256 + threadIdx.x) * 4;
    float4 f = *(const float4*)(src + i4);
    ushort4 o; o.x = f2bf(f.x); o.y = f2bf(f.y); o.z = f2bf(f.z); o.w = f2bf(f.w);
    *(ushort4*)(W6 + (size_t)z * ((size_t)D_ * D_) + i4) = o;
}

// ---------- causal depthwise conv (K=4) + silu; also emits x as bf16 ----------
__global__ __launch_bounds__(256) void conv_kernel(
    const float* __restrict__ x, const float* __restrict__ cw, const float* __restrict__ cb,
    ushort* __restrict__ xb, ushort* __restrict__ xcb)
{
    const int idx = blockIdx.x * 256 + threadIdx.x;
    const int c = idx & (D_ - 1);
    const int t = (idx >> 11) & (T_ - 1);
    const float* w = cw + c * 4;
    const float x3 = x[idx];
    float a = cb[c] + w[3] * x3;
    if (t >= 1) a += w[2] * x[idx - D_];
    if (t >= 2) a += w[1] * x[idx - 2 * D_];
    if (t >= 3) a += w[0] * x[idx - 3 * D_];
    xb[idx] = f2bf(x3);
    xcb[idx] = f2bf(a * sigm(a));
}

// ---------- 256x256 8-phase GEMM: C[M,N] = A[M,K] * W[N,K]^T  (bf16 in) ----------
// 512 thr (8 waves 2x4), BK=64, LDS 128KB double-buffered, st_16x32 swizzle,
// counted vmcnt(8) boundary, setprio around MFMA clusters.
template <bool BF16OUT>
__device__ __forceinline__ void gemm256_body(
    const ushort* __restrict__ A, const ushort* __restrict__ Bw,
    ushort* __restrict__ Cb, float* __restrict__ Cf, int bx, int by)
{
    extern __shared__ char smem[];
    const int tid = threadIdx.x;
    const int lane = tid & 63, wid = tid >> 6;
    const int wm = wid >> 2, wn = wid & 3;
    const int l15 = lane & 15, l4 = lane >> 4;
    const int brow = by * 256, bcol = bx * 256;

    // staging addressing: linear LDS dest (wave-uniform base + lane*16),
    // pre-swizzled global source col (involution: c ^= ((row>>3)&1)<<4)
    const int srow = tid >> 3;                                  // 0..63
    const int scol = ((tid & 7) * 8) ^ (((tid >> 6) & 1) << 4);
    const uint sldso = (uint)tid * 16;

    f32x4 acc[8][4] = {};

    // prologue: stage K-tiles 0 and 1
    #pragma unroll
    for (int tt = 0; tt < 2; ++tt) {
        const uint bo = (uint)tt * 65536u;
        const int k0 = tt * 64;
        #pragma unroll
        for (int j = 0; j < 4; ++j)
            gload_lds16(A + (size_t)(brow + j * 64 + srow) * D_ + (k0 + scol),
                        smem + bo + j * 8192 + sldso);
        #pragma unroll
        for (int j = 0; j < 4; ++j)
            gload_lds16(Bw + (size_t)(bcol + j * 64 + srow) * D_ + (k0 + scol),
                        smem + bo + 32768u + j * 8192 + sldso);
    }
    asm volatile("s_waitcnt vmcnt(8)" ::: "memory");
    SBAR;

    const uint colb   = (uint)((l4 * 16) ^ (((lane >> 3) & 1) << 5));  // swizzled col bytes
    const uint abase0 = (uint)(wm * 128 + l15) * 128u + colb;
    const uint bbase0 = 32768u + (uint)(wn * 64 + l15) * 128u + colb;
    const uint ldsbase = (uint)(size_t)smem;

    #pragma unroll 2
    for (int t = 0; t < 32; ++t) {
        const uint bo = ldsbase + (uint)(t & 1) * 65536u;
        const uint ab = bo + abase0, bb = bo + bbase0;
        bf16x8 a0[8], a1[8], b0[4], b1[4];
        // ---- P0: read A(m0-3) + B(n0-1); MFMA quadrant (m0-3, n0-1)
        a0[0] = dsr<0>(ab);        a0[1] = dsr<64>(ab);
        a0[2] = dsr<2048>(ab);     a0[3] = dsr<2048 + 64>(ab);
        a0[4] = dsr<4096>(ab);     a0[5] = dsr<4096 + 64>(ab);
        a0[6] = dsr<6144>(ab);     a0[7] = dsr<6144 + 64>(ab);
        b0[0] = dsr<0>(bb);        b0[1] = dsr<64>(bb);
        b0[2] = dsr<2048>(bb);     b0[3] = dsr<2048 + 64>(bb);
        SBAR;
        LGKM0;
        __builtin_amdgcn_s_setprio(1);
        #pragma unroll
        for (int ks = 0; ks < 2; ++ks)
            #pragma unroll
            for (int m = 0; m < 4; ++m)
                #pragma unroll
                for (int n = 0; n < 2; ++n)
                    acc[m][n] = __builtin_amdgcn_mfma_f32_16x16x32_bf16(
                        a0[m * 2 + ks], b0[n * 2 + ks], acc[m][n], 0, 0, 0);
        __builtin_amdgcn_sched_barrier(0);
        __builtin_amdgcn_s_setprio(0);
        SBAR;
        // ---- P1: read B(n2-3); MFMA (m0-3, n2-3)
        b1[0] = dsr<4096>(bb);     b1[1] = dsr<4096 + 64>(bb);
        b1[2] = dsr<6144>(bb);     b1[3] = dsr<6144 + 64>(bb);
        SBAR;
        LGKM0;
        __builtin_amdgcn_s_setprio(1);
        #pragma unroll
        for (int ks = 0; ks < 2; ++ks)
            #pragma unroll
            for (int m = 0; m < 4; ++m)
                #pragma unroll
                for (int n = 0; n < 2; ++n)
                    acc[m][2 + n] = __builtin_amdgcn_mfma_f32_16x16x32_bf16(
                        a0[m * 2 + ks], b1[n * 2 + ks], acc[m][2 + n], 0, 0, 0);
        __builtin_amdgcn_sched_barrier(0);
        __builtin_amdgcn_s_setprio(0);
        SBAR;
        // ---- P2: read A(m4-7); MFMA (m4-7, n0-1)
        a1[0] = dsr<8192>(ab);      a1[1] = dsr<8192 + 64>(ab);
        a1[2] = dsr<10240>(ab);     a1[3] = dsr<10240 + 64>(ab);
        a1[4] = dsr<12288>(ab);     a1[5] = dsr<12288 + 64>(ab);
        a1[6] = dsr<14336>(ab);     a1[7] = dsr<14336 + 64>(ab);
        SBAR;
        LGKM0;
        __builtin_amdgcn_s_setprio(1);
        #pragma unroll
        for (int ks = 0; ks < 2; ++ks)
            #pragma unroll
            for (int m = 0; m < 4; ++m)
                #pragma unroll
                for (int n = 0; n < 2; ++n)
                    acc[4 + m][n] = __builtin_amdgcn_mfma_f32_16x16x32_bf16(
                        a1[m * 2 + ks], b0[n * 2 + ks], acc[4 + m][n], 0, 0, 0);
        __builtin_amdgcn_sched_barrier(0);
        __builtin_amdgcn_s_setprio(0);
        SBAR;
        // ---- P3: stage K-tile t+2 into buf[t&1] (reads of tile t all done); MFMA (m4-7, n2-3)
        if (t + 2 < 32) {
            const uint bo2 = (uint)(t & 1) * 65536u;
            const int k0 = (t + 2) * 64;
            #pragma unroll
            for (int j = 0; j < 4; ++j)
                gload_lds16(A + (size_t)(brow + j * 64 + srow) * D_ + (k0 + scol),
                            smem + bo2 + j * 8192 + sldso);
            #pragma unroll
            for (int j = 0; j < 4; ++j)
                gload_lds16(Bw + (size_t)(bcol + j * 64 + srow) * D_ + (k0 + scol),
                            smem + bo2 + 32768u + j * 8192 + sldso);
        }
        SBAR;
        __builtin_amdgcn_s_setprio(1);
        #pragma unroll
        for (int ks = 0; ks < 2; ++ks)
            #pragma unroll
            for (int m = 0; m < 4; ++m)
                #pragma unroll
                for (int n = 0; n < 2; ++n)
                    acc[4 + m][2 + n] = __builtin_amdgcn_mfma_f32_16x16x32_bf16(
                        a1[m * 2 + ks], b1[n * 2 + ks], acc[4 + m][2 + n], 0, 0, 0);
        __builtin_amdgcn_sched_barrier(0);
        __builtin_amdgcn_s_setprio(0);
        // boundary: own future loads stay in flight (counted), publish tile t+1
        if (t < 31) {
            if (t < 30) asm volatile("s_waitcnt vmcnt(8)" ::: "memory");
            else        asm volatile("s_waitcnt vmcnt(0)" ::: "memory");
            SBAR;
        }
    }

    #pragma unroll
    for (int m = 0; m < 8; ++m)
        #pragma unroll
        for (int n = 0; n < 4; ++n) {
            const int row = brow + wm * 128 + m * 16 + l4 * 4;
            const int col = bcol + wn * 64 + n * 16 + l15;
            #pragma unroll
            for (int r = 0; r < 4; ++r) {
                if (BF16OUT) Cb[(size_t)(row + r) * D_ + col] = f2bf(acc[m][n][r]);
                else         Cf[(size_t)(row + r) * D_ + col] = acc[m][n][r];
            }
        }
}

__global__ __launch_bounds__(512, 2) void gemm5_kernel(
    const ushort* __restrict__ xb, const ushort* __restrict__ xcb,
    const ushort* __restrict__ W6, ushort* __restrict__ Obuf)
{
    // bijective XCD swizzle over 640 = 8 * 80 blocks
    const int g = (blockIdx.z * 16 + blockIdx.y) * 8 + blockIdx.x;
    const int ns = (g & 7) * 80 + (g >> 3);
    const int z = ns >> 7, rem = ns & 127, by = rem >> 3, bx = rem & 7;
    const ushort* Aop = (z < 3) ? xb : xcb;
    gemm256_body<true>(Aop, W6 + (size_t)z * ((size_t)D_ * D_),
                       Obuf + (size_t)z * ((size_t)M_ * D_), nullptr, bx, by);
}

__global__ __launch_bounds__(512, 2) void gemm_out_kernel(
    const ushort* __restrict__ gated, const ushort* __restrict__ W6, float* __restrict__ out)
{
    const int g = blockIdx.y * 8 + blockIdx.x;
    const int ns = (g & 7) * 16 + (g >> 3);
    const int by = ns >> 3, bx = ns & 7;
    gemm256_body<false>(gated, W6 + (size_t)5 * ((size_t)D_ * D_), nullptr, out, bx, by);
}

// ---------- gamma = sigmoid(x_conv . Wg[h] + b_g[h]) — LDS-staged, 8 tokens/block ----------
__global__ __launch_bounds__(256) void gamma_kernel(
    const ushort* __restrict__ xcb, const float* __restrict__ Wg,
    const float* __restrict__ bg, float* __restrict__ gamma)
{
    __shared__ ushort xs[8 * D_];          // 32 KB
    const int tid = threadIdx.x;
    const int tok0 = blockIdx.x * 8;
    const uint4* gsrc = (const uint4*)(xcb + (size_t)tok0 * D_);
    #pragma unroll
    for (int j = 0; j < 8; ++j)
        ((uint4*)xs)[j * 256 + tid] = gsrc[j * 256 + tid];
    __syncthreads();
    const int tok = tid >> 5;              // 0..7
    const int h = (tid >> 1) & 15;
    const int half = tid & 1;
    const ushort* xr = xs + tok * D_ + half * 1024;
    const float* wr = Wg + (size_t)h * D_ + half * 1024;
    float acc = 0.f;
    #pragma unroll 4
    for (int i = 0; i < 1024; i += 8) {
        uint4 u = *(const uint4*)(xr + i);
        float4 w0 = *(const float4*)(wr + i);
        float4 w1 = *(const float4*)(wr + i + 4);
        acc += bflo(u.x) * w0.x + bfhi(u.x) * w0.y + bflo(u.y) * w0.z + bfhi(u.y) * w0.w;
        acc += bflo(u.z) * w1.x + bfhi(u.z) * w1.y + bflo(u.w) * w1.z + bfhi(u.w) * w1.w;
    }
    acc += __shfl_xor(acc, 1);
    if (!half) gamma[(size_t)(tok0 + tok) * H_ + h] = sigm(acc + bg[h]);
}

// ---------- bterm = sigmoid(igp + b_ig) * l2norm(k) * v ----------
__global__ __launch_bounds__(256) void bterm_kernel(
    const ushort* __restrict__ kb, const ushort* __restrict__ vb,
    const ushort* __restrict__ igb, const float* __restrict__ big,
    float* __restrict__ bt)
{
    const int token = blockIdx.x;
    const int tid = threadIdx.x;              // 16 threads per head (8 elems each)
    const int c0 = tid * 8;
    const size_t base = (size_t)token * D_ + c0;
    uint4 ku = *(const uint4*)(kb + base);
    uint4 vu = *(const uint4*)(vb + base);
    uint4 iu = *(const uint4*)(igb + base);
    float kf[8] = { bflo(ku.x), bfhi(ku.x), bflo(ku.y), bfhi(ku.y),
                    bflo(ku.z), bfhi(ku.z), bflo(ku.w), bfhi(ku.w) };
    float vf[8] = { bflo(vu.x), bfhi(vu.x), bflo(vu.y), bfhi(vu.y),
                    bflo(vu.z), bfhi(vu.z), bflo(vu.w), bfhi(vu.w) };
    float gf[8] = { bflo(iu.x), bfhi(iu.x), bflo(iu.y), bfhi(iu.y),
                    bflo(iu.z), bfhi(iu.z), bflo(iu.w), bfhi(iu.w) };
    float ss = 0.f;
    #pragma unroll
    for (int j = 0; j < 8; ++j) ss += kf[j] * kf[j];
    #pragma unroll
    for (int o = 1; o < 16; o <<= 1) ss += __shfl_xor(ss, o);
    const float sc = 1.f / fmaxf(sqrtf(ss), 1e-12f);
    float ot[8];
    #pragma unroll
    for (int j = 0; j < 8; ++j)
        ot[j] = sigm(gf[j] + big[c0 + j]) * (kf[j] * sc) * vf[j];
    float4 o0 = { ot[0], ot[1], ot[2], ot[3] };
    float4 o1 = { ot[4], ot[5], ot[6], ot[7] };
    *(float4*)(bt + base) = o0;
    *(float4*)(bt + base + 4) = o1;
}

// ---------- chunked parallel scan: mem[t] = gamma[t]*mem[t-1] + bt[t] ----------
__global__ __launch_bounds__(256) void scan1_kernel(
    const float* __restrict__ bt, const float* __restrict__ gam,
    float* __restrict__ Ab, float* __restrict__ Sb)
{
    const int c = blockIdx.x * 256 + threadIdx.x;
    const int ch = blockIdx.y, b = blockIdx.z;
    const int h = c >> 7;
    const float* g = gam + ((size_t)b * T_ + ch * CL_) * H_ + h;
    const float* p = bt + ((size_t)b * T_ + ch * CL_) * D_ + c;
    float a = 1.f, s = 0.f;
    #pragma unroll 8
    for (int i = 0; i < CL_; ++i) {
        const float gv = g[(size_t)i * H_];
        s = fmaf(gv, s, p[(size_t)i * D_]);
        a *= gv;
    }
    const size_t o = ((size_t)b * NC_ + ch) * D_ + c;
    Ab[o] = a; Sb[o] = s;
}

__global__ __launch_bounds__(256) void scan2_kernel(
    const float* __restrict__ Ab, const float* __restrict__ Sb, float* __restrict__ carry)
{
    const int idx = blockIdx.x * 256 + threadIdx.x;   // b*D + c
    const int b = idx >> 11, c = idx & (D_ - 1);
    float run = 0.f;
    #pragma unroll
    for (int ch = 0; ch < NC_; ++ch) {
        const size_t o = ((size_t)b * NC_ + ch) * D_ + c;
        carry[o] = run;
        run = fmaf(Ab[o], run, Sb[o]);
    }
}

__global__ __launch_bounds__(256) void scan3_kernel(
    float* __restrict__ bt, const float* __restrict__ gam, const float* __restrict__ carry)
{
    const int c = blockIdx.x * 256 + threadIdx.x;
    const int ch = blockIdx.y, b = blockIdx.z;
    const int h = c >> 7;
    const float* g = gam + ((size_t)b * T_ + ch * CL_) * H_ + h;
    float* p = bt + ((size_t)b * T_ + ch * CL_) * D_ + c;
    float m = carry[((size_t)b * NC_ + ch) * D_ + c];
    #pragma unroll 8
    for (int i = 0; i < CL_; ++i) {
        m = fmaf(g[(size_t)i * H_], m, p[(size_t)i * D_]);
        p[(size_t)i * D_] = m;
    }
}

// ---------- GN(mem)*l2norm(q) -> GN -> *sigmoid(og) -> bf16; also rnn_state ----------
__global__ __launch_bounds__(256) void norm_kernel(
    const float* __restrict__ mem, const ushort* __restrict__ qb,
    const ushort* __restrict__ ogb, const float* __restrict__ bog,
    const float* __restrict__ mnw, const float* __restrict__ mnb,
    const float* __restrict__ gnw, const float* __restrict__ gnb,
    ushort* __restrict__ gated, float* __restrict__ rnn)
{
    const int token = blockIdx.x;
    const int tid = threadIdx.x;
    const int c0 = tid * 8;
    const size_t base = (size_t)token * D_ + c0;
    float mm[8];
    { float4 a = *(const float4*)(mem + base); float4 b2 = *(const float4*)(mem + base + 4);
      mm[0]=a.x; mm[1]=a.y; mm[2]=a.z; mm[3]=a.w; mm[4]=b2.x; mm[5]=b2.y; mm[6]=b2.z; mm[7]=b2.w; }
    float s1 = 0.f, s2 = 0.f;
    #pragma unroll
    for (int j = 0; j < 8; ++j) { s1 += mm[j]; s2 += mm[j] * mm[j]; }
    #pragma unroll
    for (int o = 1; o < 16; o <<= 1) { s1 += __shfl_xor(s1, o); s2 += __shfl_xor(s2, o); }
    const float mu = s1 * (1.f / 128.f);
    const float inv = 1.f / sqrtf(fmaxf(s2 * (1.f / 128.f) - mu * mu, 0.f) + EPS_);
    uint4 qu = *(const uint4*)(qb + base);
    float qf[8] = { bflo(qu.x), bfhi(qu.x), bflo(qu.y), bfhi(qu.y),
                    bflo(qu.z), bfhi(qu.z), bflo(qu.w), bfhi(qu.w) };
    float qs = 0.f;
    #pragma unroll
    for (int j = 0; j < 8; ++j) qs += qf[j] * qf[j];
    #pragma unroll
    for (int o = 1; o < 16; o <<= 1) qs += __shfl_xor(qs, o);
    const float qsc = 1.f / fmaxf(sqrtf(qs), 1e-12f);
    float ov[8]; float t1 = 0.f, t2 = 0.f;
    #pragma unroll
    for (int j = 0; j < 8; ++j) {
        const float mn = (mm[j] - mu) * inv * mnw[c0 + j] + mnb[c0 + j];
        ov[j] = mn * (qf[j] * qsc);
        t1 += ov[j]; t2 += ov[j] * ov[j];
    }
    #pragma unroll
    for (int o = 1; o < 16; o <<= 1) { t1 += __shfl_xor(t1, o); t2 += __shfl_xor(t2, o); }
    const float mu2 = t1 * (1.f / 128.f);
    const float inv2 = 1.f / sqrtf(fmaxf(t2 * (1.f / 128.f) - mu2 * mu2, 0.f) + EPS_);
    uint4 ou = *(const uint4*)(ogb + base);
    float of[8] = { bflo(ou.x), bfhi(ou.x), bflo(ou.y), bfhi(ou.y),
                    bflo(ou.z), bfhi(ou.z), bflo(ou.w), bfhi(ou.w) };
    uint pk[4];
    #pragma unroll
    for (int j2 = 0; j2 < 4; ++j2) {
        const int e0 = 2 * j2, e1 = 2 * j2 + 1;
        float g0 = ((ov[e0] - mu2) * inv2 * gnw[c0 + e0] + gnb[c0 + e0]) * sigm(of[e0] + bog[c0 + e0]);
        float g1 = ((ov[e1] - mu2) * inv2 * gnw[c0 + e1] + gnb[c0 + e1]) * sigm(of[e1] + bog[c0 + e1]);
        pk[j2] = (uint)f2bf(g0) | ((uint)f2bf(g1) << 16);
    }
    uint4 st = { pk[0], pk[1], pk[2], pk[3] };
    *(uint4*)(gated + base) = st;
    if ((token & (T_ - 1)) == T_ - 1) {       // t == T-1: raw mem -> next_rnn_state
        float* r = rnn + (size_t)(token >> 11) * D_ + c0;
        float4 r0 = { mm[0], mm[1], mm[2], mm[3] };
        float4 r1 = { mm[4], mm[5], mm[6], mm[7] };
        *(float4*)r = r0; *(float4*)(r + 4) = r1;
    }
}

// ---------- conv cache: x^T last K-1 timesteps ----------
__global__ __launch_bounds__(256) void cache_kernel(const float* __restrict__ x, float* __restrict__ out)
{
    const int idx = blockIdx.x * 256 + threadIdx.x;  // B*D*3
    if (idx >= B_ * D_ * 3) return;
    const int b = idx / (D_ * 3);
    const int rem = idx - b * (D_ * 3);
    const int c = rem / 3;
    const int j = rem - c * 3;
    out[idx] = x[((size_t)b * T_ + (T_ - 3 + j)) * D_ + c];
}

extern "C" void kernel_launch(void* const* d_in, const int* in_sizes, int n_in,
                              void* d_out, int out_size, void* d_ws, size_t ws_size,
                              hipStream_t stream)
{
    const float* x   = (const float*)d_in[0];
    const float* Wq  = (const float*)d_in[1];
    const float* Wk  = (const float*)d_in[2];
    const float* Wv  = (const float*)d_in[3];
    const float* Wo  = (const float*)d_in[4];
    const float* cw  = (const float*)d_in[5];
    const float* cb  = (const float*)d_in[6];
    const float* Wig = (const float*)d_in[7];
    const float* big = (const float*)d_in[8];
    const float* Wog = (const float*)d_in[9];
    const float* bog = (const float*)d_in[10];
    const float* Wg  = (const float*)d_in[11];
    const float* bg  = (const float*)d_in[12];
    const float* gnw = (const float*)d_in[13];
    const float* gnb = (const float*)d_in[14];
    const float* mnw = (const float*)d_in[15];
    const float* mnb = (const float*)d_in[16];

    char* ws = (char*)d_ws;
    ushort* W6   = (ushort*)ws;                                         // 50,331,648 B
    ushort* xb   = (ushort*)(ws + 50331648);                            // 16,777,216
    ushort* xcb  = (ushort*)(ws + 50331648 + 16777216);                 // 16,777,216
    ushort* Obuf = (ushort*)(ws + 50331648 + 2 * 16777216);             // 5 x 16,777,216
    float*  gam  = (float*)(ws + 50331648 + 7 * 16777216);              // 262,144
    float*  bt   = (float*)(ws + 50331648 + 7 * 16777216 + 262144);     // 33,554,432

    ushort* q    = Obuf;
    ushort* k    = Obuf + (size_t)M_ * D_;
    ushort* v    = Obuf + 2 * (size_t)M_ * D_;
    ushort* igp  = Obuf + 3 * (size_t)M_ * D_;
    ushort* ogp  = Obuf + 4 * (size_t)M_ * D_;
    ushort* gated = k;                         // k dead after bterm_kernel
    float*  Ab   = (float*)v;                  // v dead after bterm_kernel (1.5MB << 16.8MB)
    float*  Sb   = Ab + (size_t)B_ * NC_ * D_;
    float*  carry= Sb + (size_t)B_ * NC_ * D_;

    float* out  = (float*)d_out;
    float* rnn  = out + (size_t)M_ * D_;
    float* cach = rnn + B_ * D_;

    (void)hipFuncSetAttribute((const void*)gemm5_kernel,
                              hipFuncAttributeMaxDynamicSharedMemorySize, 131072);
    (void)hipFuncSetAttribute((const void*)gemm_out_kernel,
                              hipFuncAttributeMaxDynamicSharedMemorySize, 131072);

    cvtw_kernel<<<dim3(4096, 6), 256, 0, stream>>>(Wq, Wk, Wv, Wig, Wog, Wo, W6);
    conv_kernel<<<dim3(M_ * D_ / 256), 256, 0, stream>>>(x, cw, cb, xb, xcb);
    gemm5_kernel<<<dim3(8, 16, 5), 512, 131072, stream>>>(xb, xcb, W6, Obuf);
    gamma_kernel<<<dim3(M_ / 8), 256, 0, stream>>>(xcb, Wg, bg, gam);
    bterm_kernel<<<dim3(M_), 256, 0, stream>>>(k, v, igp, big, bt);
    scan1_kernel<<<dim3(8, NC_, 2), 256, 0, stream>>>(bt, gam, Ab, Sb);
    scan2_kernel<<<dim3(16), 256, 0, stream>>>(Ab, Sb, carry);
    scan3_kernel<<<dim3(8, NC_, 2), 256, 0, stream>>>(bt, gam, carry);
    norm_kernel<<<dim3(M_), 256, 0, stream>>>(bt, q, ogp, bog, mnw, mnb, gnw, gnb, gated, rnn);
    gemm_out_kernel<<<dim3(8, 16), 512, 131072, stream>>>(gated, W6, out);
    cache_kernel<<<dim3(48), 256, 0, stream>>>(x, cach);
}

// Round 4
// 433.643 us; speedup vs baseline: 1.3616x; 1.0646x over previous
//
#include <hip/hip_runtime.h>
#include <math.h>

#define B_ 2
#define T_ 2048
#define D_ 2048
#define H_ 16
#define M_ 4096          // B*T
#define TD_ (T_ * D_)
#define EPS_ 1e-5f
#define NC_ 32           // scan chunks
#define CL_ 64           // scan chunk length

typedef __bf16 bf16x8 __attribute__((ext_vector_type(8)));
typedef float f32x4 __attribute__((ext_vector_type(4)));

__device__ __forceinline__ float sigm(float z) { return 1.f / (1.f + __expf(-z)); }

__device__ __forceinline__ ushort f2bf(float f) {  // RNE f32 -> bf16 bits
    union { float f; uint u; } x; x.f = f;
    uint r = x.u + 0x7fffu + ((x.u >> 16) & 1u);
    return (ushort)(r >> 16);
}
__device__ __forceinline__ float bflo(uint u) { union { uint u; float f; } x; x.u = u << 16; return x.f; }
__device__ __forceinline__ float bfhi(uint u) { union { uint u; float f; } x; x.u = u & 0xffff0000u; return x.f; }

__device__ __forceinline__ void gload_lds16(const void* g, void* l) {
    __builtin_amdgcn_global_load_lds((const __attribute__((address_space(1))) void*)g,
                                     (__attribute__((address_space(3))) void*)l, 16, 0, 0);
}

template <int IMM>
__device__ __forceinline__ bf16x8 dsr(uint addr) {
    int4 d;
    asm volatile("ds_read_b128 %0, %1 offset:%2" : "=v"(d) : "v"(addr), "n"(IMM));
    return __builtin_bit_cast(bf16x8, d);
}
#define LGKM0 do { asm volatile("s_waitcnt lgkmcnt(0)" ::: "memory"); __builtin_amdgcn_sched_barrier(0); } while (0)
#define SBAR  __builtin_amdgcn_s_barrier()

// ---------- weights f32 -> bf16 (order: Wq,Wk,Wv,Wig,Wog,Wo) ----------
__global__ __launch_bounds__(256) void cvtw_kernel(
    const float* __restrict__ Wq, const float* __restrict__ Wk, const float* __restrict__ Wv,
    const float* __restrict__ Wig, const float* __restrict__ Wog, const float* __restrict__ Wo,
    ushort* __restrict__ W6)
{
    const int z = blockIdx.y;
    const float* src = z == 0 ? Wq : z == 1 ? Wk : z == 2 ? Wv : z == 3 ? Wig : z == 4 ? Wog : Wo;
    const int i4 = (blockIdx.x * 256 + threadIdx.x) * 4;
    float4 f = *(const float4*)(src + i4);
    ushort4 o; o.x = f2bf(f.x); o.y = f2bf(f.y); o.z = f2bf(f.z); o.w = f2bf(f.w);
    *(ushort4*)(W6 + (size_t)z * ((size_t)D_ * D_) + i4) = o;
}

// ---------- causal depthwise conv (K=4) + silu; also emits x as bf16 ----------
__global__ __launch_bounds__(256) void conv_kernel(
    const float* __restrict__ x, const float* __restrict__ cw, const float* __restrict__ cb,
    ushort* __restrict__ xb, ushort* __restrict__ xcb)
{
    const int idx = blockIdx.x * 256 + threadIdx.x;
    const int c = idx & (D_ - 1);
    const int t = (idx >> 11) & (T_ - 1);
    const float* w = cw + c * 4;
    const float x3 = x[idx];
    float a = cb[c] + w[3] * x3;
    if (t >= 1) a += w[2] * x[idx - D_];
    if (t >= 2) a += w[1] * x[idx - 2 * D_];
    if (t >= 3) a += w[0] * x[idx - 3 * D_];
    xb[idx] = f2bf(x3);
    xcb[idx] = f2bf(a * sigm(a));
}

// ---------- 256x256 8-phase GEMM: C[M,N] = A[M,K] * W[N,K]^T  (bf16 in) ----------
// 512 thr (8 waves 2x4), BK=64, LDS 128KB double-buffered,
// 3-bit row XOR-swizzle (byte ^= (row&7)<<4) on staging source + ds_read addr,
// counted vmcnt(8) boundary, setprio around MFMA clusters.
template <bool BF16OUT>
__device__ __forceinline__ void gemm256_body(
    const ushort* __restrict__ A, const ushort* __restrict__ Bw,
    ushort* __restrict__ Cb, float* __restrict__ Cf, int bx, int by)
{
    extern __shared__ char smem[];
    const int tid = threadIdx.x;
    const int lane = tid & 63, wid = tid >> 6;
    const int wm = wid >> 2, wn = wid & 3;
    const int l15 = lane & 15, l4 = lane >> 4;
    const int brow = by * 256, bcol = bx * 256;

    // staging: linear LDS dest (tid*16 bytes); pre-swizzled global source col.
    // LDS(row, cb) holds global element-bytes cb ^ ((row&7)<<4).
    const int srow = tid >> 3;                                  // 0..63
    const int scol = ((tid & 7) * 8) ^ (((tid >> 3) & 7) << 3); // elements
    const uint sldso = (uint)tid * 16;

    f32x4 acc[8][4] = {};

    // prologue: stage K-tiles 0 and 1
    #pragma unroll
    for (int tt = 0; tt < 2; ++tt) {
        const uint bo = (uint)tt * 65536u;
        const int k0 = tt * 64;
        #pragma unroll
        for (int j = 0; j < 4; ++j)
            gload_lds16(A + (size_t)(brow + j * 64 + srow) * D_ + (k0 + scol),
                        smem + bo + j * 8192 + sldso);
        #pragma unroll
        for (int j = 0; j < 4; ++j)
            gload_lds16(Bw + (size_t)(bcol + j * 64 + srow) * D_ + (k0 + scol),
                        smem + bo + 32768u + j * 8192 + sldso);
    }
    asm volatile("s_waitcnt vmcnt(8)" ::: "memory");
    SBAR;

    // read addressing: row = <base> + l15, col bytes (kk*64 + l4*16) ^ ((l15&7)<<4).
    // kk lives in the address register (XOR touches bit 6); row-block offsets
    // (multiples of 2048, row&7 invariant) stay as ds_read immediates.
    const uint r7  = (uint)((l15 & 7) << 4);
    const uint ca0 = (uint)(l4 * 16) ^ r7;
    const uint ca1 = (uint)(64 + l4 * 16) ^ r7;
    const uint arow = (uint)(wm * 128 + l15) * 128u;
    const uint brw  = 32768u + (uint)(wn * 64 + l15) * 128u;
    const uint ldsbase = (uint)(size_t)smem;

    #pragma unroll 2
    for (int t = 0; t < 32; ++t) {
        const uint bo = ldsbase + (uint)(t & 1) * 65536u;
        const uint ab0 = bo + arow + ca0, ab1 = bo + arow + ca1;
        const uint bb0 = bo + brw + ca0,  bb1 = bo + brw + ca1;
        bf16x8 a0[8], a1[8], b0[4], b1[4];
        // ---- P0: read A(m0-3) + B(n0-1); MFMA quadrant (m0-3, n0-1)
        a0[0] = dsr<0>(ab0);        a0[1] = dsr<0>(ab1);
        a0[2] = dsr<2048>(ab0);     a0[3] = dsr<2048>(ab1);
        a0[4] = dsr<4096>(ab0);     a0[5] = dsr<4096>(ab1);
        a0[6] = dsr<6144>(ab0);     a0[7] = dsr<6144>(ab1);
        b0[0] = dsr<0>(bb0);        b0[1] = dsr<0>(bb1);
        b0[2] = dsr<2048>(bb0);     b0[3] = dsr<2048>(bb1);
        SBAR;
        LGKM0;
        __builtin_amdgcn_s_setprio(1);
        #pragma unroll
        for (int ks = 0; ks < 2; ++ks)
            #pragma unroll
            for (int m = 0; m < 4; ++m)
                #pragma unroll
                for (int n = 0; n < 2; ++n)
                    acc[m][n] = __builtin_amdgcn_mfma_f32_16x16x32_bf16(
                        a0[m * 2 + ks], b0[n * 2 + ks], acc[m][n], 0, 0, 0);
        __builtin_amdgcn_sched_barrier(0);
        __builtin_amdgcn_s_setprio(0);
        SBAR;
        // ---- P1: read B(n2-3); MFMA (m0-3, n2-3)
        b1[0] = dsr<4096>(bb0);     b1[1] = dsr<4096>(bb1);
        b1[2] = dsr<6144>(bb0);     b1[3] = dsr<6144>(bb1);
        SBAR;
        LGKM0;
        __builtin_amdgcn_s_setprio(1);
        #pragma unroll
        for (int ks = 0; ks < 2; ++ks)
            #pragma unroll
            for (int m = 0; m < 4; ++m)
                #pragma unroll
                for (int n = 0; n < 2; ++n)
                    acc[m][2 + n] = __builtin_amdgcn_mfma_f32_16x16x32_bf16(
                        a0[m * 2 + ks], b1[n * 2 + ks], acc[m][2 + n], 0, 0, 0);
        __builtin_amdgcn_sched_barrier(0);
        __builtin_amdgcn_s_setprio(0);
        SBAR;
        // ---- P2: read A(m4-7); MFMA (m4-7, n0-1)
        a1[0] = dsr<8192>(ab0);      a1[1] = dsr<8192>(ab1);
        a1[2] = dsr<10240>(ab0);     a1[3] = dsr<10240>(ab1);
        a1[4] = dsr<12288>(ab0);     a1[5] = dsr<12288>(ab1);
        a1[6] = dsr<14336>(ab0);     a1[7] = dsr<14336>(ab1);
        SBAR;
        LGKM0;
        __builtin_amdgcn_s_setprio(1);
        #pragma unroll
        for (int ks = 0; ks < 2; ++ks)
            #pragma unroll
            for (int m = 0; m < 4; ++m)
                #pragma unroll
                for (int n = 0; n < 2; ++n)
                    acc[4 + m][n] = __builtin_amdgcn_mfma_f32_16x16x32_bf16(
                        a1[m * 2 + ks], b0[n * 2 + ks], acc[4 + m][n], 0, 0, 0);
        __builtin_amdgcn_sched_barrier(0);
        __builtin_amdgcn_s_setprio(0);
        SBAR;
        // ---- P3: stage K-tile t+2 into buf[t&1]; MFMA (m4-7, n2-3)
        if (t + 2 < 32) {
            const uint bo2 = (uint)(t & 1) * 65536u;
            const int k0 = (t + 2) * 64;
            #pragma unroll
            for (int j = 0; j < 4; ++j)
                gload_lds16(A + (size_t)(brow + j * 64 + srow) * D_ + (k0 + scol),
                            smem + bo2 + j * 8192 + sldso);
            #pragma unroll
            for (int j = 0; j < 4; ++j)
                gload_lds16(Bw + (size_t)(bcol + j * 64 + srow) * D_ + (k0 + scol),
                            smem + bo2 + 32768u + j * 8192 + sldso);
        }
        SBAR;
        __builtin_amdgcn_s_setprio(1);
        #pragma unroll
        for (int ks = 0; ks < 2; ++ks)
            #pragma unroll
            for (int m = 0; m < 4; ++m)
                #pragma unroll
                for (int n = 0; n < 2; ++n)
                    acc[4 + m][2 + n] = __builtin_amdgcn_mfma_f32_16x16x32_bf16(
                        a1[m * 2 + ks], b1[n * 2 + ks], acc[4 + m][2 + n], 0, 0, 0);
        __builtin_amdgcn_sched_barrier(0);
        __builtin_amdgcn_s_setprio(0);
        // boundary: own future loads stay in flight (counted), publish tile t+1
        if (t < 31) {
            if (t < 30) asm volatile("s_waitcnt vmcnt(8)" ::: "memory");
            else        asm volatile("s_waitcnt vmcnt(0)" ::: "memory");
            SBAR;
        }
    }

    #pragma unroll
    for (int m = 0; m < 8; ++m)
        #pragma unroll
        for (int n = 0; n < 4; ++n) {
            const int row = brow + wm * 128 + m * 16 + l4 * 4;
            const int col = bcol + wn * 64 + n * 16 + l15;
            #pragma unroll
            for (int r = 0; r < 4; ++r) {
                if (BF16OUT) Cb[(size_t)(row + r) * D_ + col] = f2bf(acc[m][n][r]);
                else         Cf[(size_t)(row + r) * D_ + col] = acc[m][n][r];
            }
        }
}

__global__ __launch_bounds__(512, 2) void gemm5_kernel(
    const ushort* __restrict__ xb, const ushort* __restrict__ xcb,
    const ushort* __restrict__ W6, ushort* __restrict__ Obuf)
{
    // bijective XCD swizzle over 640 = 8 * 80 blocks
    const int g = (blockIdx.z * 16 + blockIdx.y) * 8 + blockIdx.x;
    const int ns = (g & 7) * 80 + (g >> 3);
    const int z = ns >> 7, rem = ns & 127, by = rem >> 3, bx = rem & 7;
    const ushort* Aop = (z < 3) ? xb : xcb;
    gemm256_body<true>(Aop, W6 + (size_t)z * ((size_t)D_ * D_),
                       Obuf + (size_t)z * ((size_t)M_ * D_), nullptr, bx, by);
}

__global__ __launch_bounds__(512, 2) void gemm_out_kernel(
    const ushort* __restrict__ gated, const ushort* __restrict__ W6, float* __restrict__ out)
{
    const int g = blockIdx.y * 8 + blockIdx.x;
    const int ns = (g & 7) * 16 + (g >> 3);
    const int by = ns >> 3, bx = ns & 7;
    gemm256_body<false>(gated, W6 + (size_t)5 * ((size_t)D_ * D_), nullptr, out, bx, by);
}

// ---------- gamma = sigmoid(x_conv . Wg[h] + b_g[h]) — LDS-staged, 8 tokens/block ----------
__global__ __launch_bounds__(256) void gamma_kernel(
    const ushort* __restrict__ xcb, const float* __restrict__ Wg,
    const float* __restrict__ bg, float* __restrict__ gamma)
{
    __shared__ ushort xs[8 * D_];          // 32 KB
    const int tid = threadIdx.x;
    const int tok0 = blockIdx.x * 8;
    const uint4* gsrc = (const uint4*)(xcb + (size_t)tok0 * D_);
    #pragma unroll
    for (int j = 0; j < 8; ++j)
        ((uint4*)xs)[j * 256 + tid] = gsrc[j * 256 + tid];
    __syncthreads();
    const int tok = tid >> 5;              // 0..7
    const int h = (tid >> 1) & 15;
    const int half = tid & 1;
    const ushort* xr = xs + tok * D_ + half * 1024;
    const float* wr = Wg + (size_t)h * D_ + half * 1024;
    float acc = 0.f;
    #pragma unroll 4
    for (int i = 0; i < 1024; i += 8) {
        uint4 u = *(const uint4*)(xr + i);
        float4 w0 = *(const float4*)(wr + i);
        float4 w1 = *(const float4*)(wr + i + 4);
        acc += bflo(u.x) * w0.x + bfhi(u.x) * w0.y + bflo(u.y) * w0.z + bfhi(u.y) * w0.w;
        acc += bflo(u.z) * w1.x + bfhi(u.z) * w1.y + bflo(u.w) * w1.z + bfhi(u.w) * w1.w;
    }
    acc += __shfl_xor(acc, 1);
    if (!half) gamma[(size_t)(tok0 + tok) * H_ + h] = sigm(acc + bg[h]);
}

// ---------- bterm = sigmoid(igp + b_ig) * l2norm(k) * v ----------
__global__ __launch_bounds__(256) void bterm_kernel(
    const ushort* __restrict__ kb, const ushort* __restrict__ vb,
    const ushort* __restrict__ igb, const float* __restrict__ big,
    float* __restrict__ bt)
{
    const int token = blockIdx.x;
    const int tid = threadIdx.x;              // 16 threads per head (8 elems each)
    const int c0 = tid * 8;
    const size_t base = (size_t)token * D_ + c0;
    uint4 ku = *(const uint4*)(kb + base);
    uint4 vu = *(const uint4*)(vb + base);
    uint4 iu = *(const uint4*)(igb + base);
    float kf[8] = { bflo(ku.x), bfhi(ku.x), bflo(ku.y), bfhi(ku.y),
                    bflo(ku.z), bfhi(ku.z), bflo(ku.w), bfhi(ku.w) };
    float vf[8] = { bflo(vu.x), bfhi(vu.x), bflo(vu.y), bfhi(vu.y),
                    bflo(vu.z), bfhi(vu.z), bflo(vu.w), bfhi(vu.w) };
    float gf[8] = { bflo(iu.x), bfhi(iu.x), bflo(iu.y), bfhi(iu.y),
                    bflo(iu.z), bfhi(iu.z), bflo(iu.w), bfhi(iu.w) };
    float ss = 0.f;
    #pragma unroll
    for (int j = 0; j < 8; ++j) ss += kf[j] * kf[j];
    #pragma unroll
    for (int o = 1; o < 16; o <<= 1) ss += __shfl_xor(ss, o);
    const float sc = 1.f / fmaxf(sqrtf(ss), 1e-12f);
    float ot[8];
    #pragma unroll
    for (int j = 0; j < 8; ++j)
        ot[j] = sigm(gf[j] + big[c0 + j]) * (kf[j] * sc) * vf[j];
    float4 o0 = { ot[0], ot[1], ot[2], ot[3] };
    float4 o1 = { ot[4], ot[5], ot[6], ot[7] };
    *(float4*)(bt + base) = o0;
    *(float4*)(bt + base + 4) = o1;
}

// ---------- chunked parallel scan: mem[t] = gamma[t]*mem[t-1] + bt[t] ----------
__global__ __launch_bounds__(256) void scan1_kernel(
    const float* __restrict__ bt, const float* __restrict__ gam,
    float* __restrict__ Ab, float* __restrict__ Sb)
{
    const int c = blockIdx.x * 256 + threadIdx.x;
    const int ch = blockIdx.y, b = blockIdx.z;
    const int h = c >> 7;
    const float* g = gam + ((size_t)b * T_ + ch * CL_) * H_ + h;
    const float* p = bt + ((size_t)b * T_ + ch * CL_) * D_ + c;
    float a = 1.f, s = 0.f;
    #pragma unroll 8
    for (int i = 0; i < CL_; ++i) {
        const float gv = g[(size_t)i * H_];
        s = fmaf(gv, s, p[(size_t)i * D_]);
        a *= gv;
    }
    const size_t o = ((size_t)b * NC_ + ch) * D_ + c;
    Ab[o] = a; Sb[o] = s;
}

__global__ __launch_bounds__(256) void scan2_kernel(
    const float* __restrict__ Ab, const float* __restrict__ Sb, float* __restrict__ carry)
{
    const int idx = blockIdx.x * 256 + threadIdx.x;   // b*D + c
    const int b = idx >> 11, c = idx & (D_ - 1);
    float run = 0.f;
    #pragma unroll
    for (int ch = 0; ch < NC_; ++ch) {
        const size_t o = ((size_t)b * NC_ + ch) * D_ + c;
        carry[o] = run;
        run = fmaf(Ab[o], run, Sb[o]);
    }
}

__global__ __launch_bounds__(256) void scan3_kernel(
    float* __restrict__ bt, const float* __restrict__ gam, const float* __restrict__ carry)
{
    const int c = blockIdx.x * 256 + threadIdx.x;
    const int ch = blockIdx.y, b = blockIdx.z;
    const int h = c >> 7;
    const float* g = gam + ((size_t)b * T_ + ch * CL_) * H_ + h;
    float* p = bt + ((size_t)b * T_ + ch * CL_) * D_ + c;
    float m = carry[((size_t)b * NC_ + ch) * D_ + c];
    #pragma unroll 8
    for (int i = 0; i < CL_; ++i) {
        m = fmaf(g[(size_t)i * H_], m, p[(size_t)i * D_]);
        p[(size_t)i * D_] = m;
    }
}

// ---------- GN(mem)*l2norm(q) -> GN -> *sigmoid(og) -> bf16; also rnn_state ----------
__global__ __launch_bounds__(256) void norm_kernel(
    const float* __restrict__ mem, const ushort* __restrict__ qb,
    const ushort* __restrict__ ogb, const float* __restrict__ bog,
    const float* __restrict__ mnw, const float* __restrict__ mnb,
    const float* __restrict__ gnw, const float* __restrict__ gnb,
    ushort* __restrict__ gated, float* __restrict__ rnn)
{
    const int token = blockIdx.x;
    const int tid = threadIdx.x;
    const int c0 = tid * 8;
    const size_t base = (size_t)token * D_ + c0;
    float mm[8];
    { float4 a = *(const float4*)(mem + base); float4 b2 = *(const float4*)(mem + base + 4);
      mm[0]=a.x; mm[1]=a.y; mm[2]=a.z; mm[3]=a.w; mm[4]=b2.x; mm[5]=b2.y; mm[6]=b2.z; mm[7]=b2.w; }
    float s1 = 0.f, s2 = 0.f;
    #pragma unroll
    for (int j = 0; j < 8; ++j) { s1 += mm[j]; s2 += mm[j] * mm[j]; }
    #pragma unroll
    for (int o = 1; o < 16; o <<= 1) { s1 += __shfl_xor(s1, o); s2 += __shfl_xor(s2, o); }
    const float mu = s1 * (1.f / 128.f);
    const float inv = 1.f / sqrtf(fmaxf(s2 * (1.f / 128.f) - mu * mu, 0.f) + EPS_);
    uint4 qu = *(const uint4*)(qb + base);
    float qf[8] = { bflo(qu.x), bfhi(qu.x), bflo(qu.y), bfhi(qu.y),
                    bflo(qu.z), bfhi(qu.z), bflo(qu.w), bfhi(qu.w) };
    float qs = 0.f;
    #pragma unroll
    for (int j = 0; j < 8; ++j) qs += qf[j] * qf[j];
    #pragma unroll
    for (int o = 1; o < 16; o <<= 1) qs += __shfl_xor(qs, o);
    const float qsc = 1.f / fmaxf(sqrtf(qs), 1e-12f);
    float ov[8]; float t1 = 0.f, t2 = 0.f;
    #pragma unroll
    for (int j = 0; j < 8; ++j) {
        const float mn = (mm[j] - mu) * inv * mnw[c0 + j] + mnb[c0 + j];
        ov[j] = mn * (qf[j] * qsc);
        t1 += ov[j]; t2 += ov[j] * ov[j];
    }
    #pragma unroll
    for (int o = 1; o < 16; o <<= 1) { t1 += __shfl_xor(t1, o); t2 += __shfl_xor(t2, o); }
    const float mu2 = t1 * (1.f / 128.f);
    const float inv2 = 1.f / sqrtf(fmaxf(t2 * (1.f / 128.f) - mu2 * mu2, 0.f) + EPS_);
    uint4 ou = *(const uint4*)(ogb + base);
    float of[8] = { bflo(ou.x), bfhi(ou.x), bflo(ou.y), bfhi(ou.y),
                    bflo(ou.z), bfhi(ou.z), bflo(ou.w), bfhi(ou.w) };
    uint pk[4];
    #pragma unroll
    for (int j2 = 0; j2 < 4; ++j2) {
        const int e0 = 2 * j2, e1 = 2 * j2 + 1;
        float g0 = ((ov[e0] - mu2) * inv2 * gnw[c0 + e0] + gnb[c0 + e0]) * sigm(of[e0] + bog[c0 + e0]);
        float g1 = ((ov[e1] - mu2) * inv2 * gnw[c0 + e1] + gnb[c0 + e1]) * sigm(of[e1] + bog[c0 + e1]);
        pk[j2] = (uint)f2bf(g0) | ((uint)f2bf(g1) << 16);
    }
    uint4 st = { pk[0], pk[1], pk[2], pk[3] };
    *(uint4*)(gated + base) = st;
    if ((token & (T_ - 1)) == T_ - 1) {       // t == T-1: raw mem -> next_rnn_state
        float* r = rnn + (size_t)(token >> 11) * D_ + c0;
        float4 r0 = { mm[0], mm[1], mm[2], mm[3] };
        float4 r1 = { mm[4], mm[5], mm[6], mm[7] };
        *(float4*)r = r0; *(float4*)(r + 4) = r1;
    }
}

// ---------- conv cache: x^T last K-1 timesteps ----------
__global__ __launch_bounds__(256) void cache_kernel(const float* __restrict__ x, float* __restrict__ out)
{
    const int idx = blockIdx.x * 256 + threadIdx.x;  // B*D*3
    if (idx >= B_ * D_ * 3) return;
    const int b = idx / (D_ * 3);
    const int rem = idx - b * (D_ * 3);
    const int c = rem / 3;
    const int j = rem - c * 3;
    out[idx] = x[((size_t)b * T_ + (T_ - 3 + j)) * D_ + c];
}

extern "C" void kernel_launch(void* const* d_in, const int* in_sizes, int n_in,
                              void* d_out, int out_size, void* d_ws, size_t ws_size,
                              hipStream_t stream)
{
    const float* x   = (const float*)d_in[0];
    const float* Wq  = (const float*)d_in[1];
    const float* Wk  = (const float*)d_in[2];
    const float* Wv  = (const float*)d_in[3];
    const float* Wo  = (const float*)d_in[4];
    const float* cw  = (const float*)d_in[5];
    const float* cb  = (const float*)d_in[6];
    const float* Wig = (const float*)d_in[7];
    const float* big = (const float*)d_in[8];
    const float* Wog = (const float*)d_in[9];
    const float* bog = (const float*)d_in[10];
    const float* Wg  = (const float*)d_in[11];
    const float* bg  = (const float*)d_in[12];
    const float* gnw = (const float*)d_in[13];
    const float* gnb = (const float*)d_in[14];
    const float* mnw = (const float*)d_in[15];
    const float* mnb = (const float*)d_in[16];

    char* ws = (char*)d_ws;
    ushort* W6   = (ushort*)ws;                                         // 50,331,648 B
    ushort* xb   = (ushort*)(ws + 50331648);                            // 16,777,216
    ushort* xcb  = (ushort*)(ws + 50331648 + 16777216);                 // 16,777,216
    ushort* Obuf = (ushort*)(ws + 50331648 + 2 * 16777216);             // 5 x 16,777,216
    float*  gam  = (float*)(ws + 50331648 + 7 * 16777216);              // 262,144
    float*  bt   = (float*)(ws + 50331648 + 7 * 16777216 + 262144);     // 33,554,432

    ushort* q    = Obuf;
    ushort* k    = Obuf + (size_t)M_ * D_;
    ushort* v    = Obuf + 2 * (size_t)M_ * D_;
    ushort* igp  = Obuf + 3 * (size_t)M_ * D_;
    ushort* ogp  = Obuf + 4 * (size_t)M_ * D_;
    ushort* gated = k;                         // k dead after bterm_kernel
    float*  Ab   = (float*)v;                  // v dead after bterm_kernel (1.5MB << 16.8MB)
    float*  Sb   = Ab + (size_t)B_ * NC_ * D_;
    float*  carry= Sb + (size_t)B_ * NC_ * D_;

    float* out  = (float*)d_out;
    float* rnn  = out + (size_t)M_ * D_;
    float* cach = rnn + B_ * D_;

    (void)hipFuncSetAttribute((const void*)gemm5_kernel,
                              hipFuncAttributeMaxDynamicSharedMemorySize, 131072);
    (void)hipFuncSetAttribute((const void*)gemm_out_kernel,
                              hipFuncAttributeMaxDynamicSharedMemorySize, 131072);

    cvtw_kernel<<<dim3(4096, 6), 256, 0, stream>>>(Wq, Wk, Wv, Wig, Wog, Wo, W6);
    conv_kernel<<<dim3(M_ * D_ / 256), 256, 0, stream>>>(x, cw, cb, xb, xcb);
    gemm5_kernel<<<dim3(8, 16, 5), 512, 131072, stream>>>(xb, xcb, W6, Obuf);
    gamma_kernel<<<dim3(M_ / 8), 256, 0, stream>>>(xcb, Wg, bg, gam);
    bterm_kernel<<<dim3(M_), 256, 0, stream>>>(k, v, igp, big, bt);
    scan1_kernel<<<dim3(8, NC_, 2), 256, 0, stream>>>(bt, gam, Ab, Sb);
    scan2_kernel<<<dim3(16), 256, 0, stream>>>(Ab, Sb, carry);
    scan3_kernel<<<dim3(8, NC_, 2), 256, 0, stream>>>(bt, gam, carry);
    norm_kernel<<<dim3(M_), 256, 0, stream>>>(bt, q, ogp, bog, mnw, mnb, gnw, gnb, gated, rnn);
    gemm_out_kernel<<<dim3(8, 16), 512, 131072, stream>>>(gated, W6, out);
    cache_kernel<<<dim3(48), 256, 0, stream>>>(x, cach);
}

// Round 5
// 394.612 us; speedup vs baseline: 1.4963x; 1.0989x over previous
//
#include <hip/hip_runtime.h>
#include <math.h>

#define B_ 2
#define T_ 2048
#define D_ 2048
#define H_ 16
#define M_ 4096          // B*T
#define TD_ (T_ * D_)
#define EPS_ 1e-5f
#define NC_ 32           // scan chunks
#define CL_ 64           // scan chunk length

typedef __bf16 bf16x8 __attribute__((ext_vector_type(8)));
typedef float f32x4 __attribute__((ext_vector_type(4)));

__device__ __forceinline__ float sigm(float z) { return 1.f / (1.f + __expf(-z)); }

__device__ __forceinline__ ushort f2bf(float f) {  // RNE f32 -> bf16 bits
    union { float f; uint u; } x; x.f = f;
    uint r = x.u + 0x7fffu + ((x.u >> 16) & 1u);
    return (ushort)(r >> 16);
}
__device__ __forceinline__ float bflo(uint u) { union { uint u; float f; } x; x.u = u << 16; return x.f; }
__device__ __forceinline__ float bfhi(uint u) { union { uint u; float f; } x; x.u = u & 0xffff0000u; return x.f; }

__device__ __forceinline__ void gload_lds16(const void* g, void* l) {
    __builtin_amdgcn_global_load_lds((const __attribute__((address_space(1))) void*)g,
                                     (__attribute__((address_space(3))) void*)l, 16, 0, 0);
}

template <int IMM>
__device__ __forceinline__ bf16x8 dsr(uint addr) {
    int4 d;
    asm volatile("ds_read_b128 %0, %1 offset:%2" : "=v"(d) : "v"(addr), "n"(IMM));
    return __builtin_bit_cast(bf16x8, d);
}
#define LGKM0 do { asm volatile("s_waitcnt lgkmcnt(0)" ::: "memory"); __builtin_amdgcn_sched_barrier(0); } while (0)
#define SBAR  __builtin_amdgcn_s_barrier()

// ---------- weights f32 -> bf16 (order: Wq,Wk,Wv,Wig,Wog,Wo) ----------
__global__ __launch_bounds__(256) void cvtw_kernel(
    const float* __restrict__ Wq, const float* __restrict__ Wk, const float* __restrict__ Wv,
    const float* __restrict__ Wig, const float* __restrict__ Wog, const float* __restrict__ Wo,
    ushort* __restrict__ W6)
{
    const int z = blockIdx.y;
    const float* src = z == 0 ? Wq : z == 1 ? Wk : z == 2 ? Wv : z == 3 ? Wig : z == 4 ? Wog : Wo;
    const int i4 = (blockIdx.x * 256 + threadIdx.x) * 4;
    float4 f = *(const float4*)(src + i4);
    ushort4 o; o.x = f2bf(f.x); o.y = f2bf(f.y); o.z = f2bf(f.z); o.w = f2bf(f.w);
    *(ushort4*)(W6 + (size_t)z * ((size_t)D_ * D_) + i4) = o;
}

// ---------- causal depthwise conv (K=4) + silu; also emits x as bf16 ----------
__global__ __launch_bounds__(256) void conv_kernel(
    const float* __restrict__ x, const float* __restrict__ cw, const float* __restrict__ cb,
    ushort* __restrict__ xb, ushort* __restrict__ xcb)
{
    const int idx = blockIdx.x * 256 + threadIdx.x;
    const int c = idx & (D_ - 1);
    const int t = (idx >> 11) & (T_ - 1);
    const float* w = cw + c * 4;
    const float x3 = x[idx];
    float a = cb[c] + w[3] * x3;
    if (t >= 1) a += w[2] * x[idx - D_];
    if (t >= 2) a += w[1] * x[idx - 2 * D_];
    if (t >= 3) a += w[0] * x[idx - 3 * D_];
    xb[idx] = f2bf(x3);
    xcb[idx] = f2bf(a * sigm(a));
}

// ---------- 256x128 2-phase GEMM: C[M,N] = A[M,K] * W[N,K]^T  (bf16 in) ----------
// 512 thr (8 waves 4x2), BK=64, LDS 96KB double-buffered (48KB/buf: A 32KB, B 16KB),
// 3-bit row XOR-swizzle (byte ^= (row&7)<<4) on staging source + ds_read addr,
// staging after P1 MFMA, counted vmcnt(6) boundary, setprio around MFMA clusters.
template <bool BF16OUT>
__device__ __forceinline__ void gemm256_body(
    const ushort* __restrict__ A, const ushort* __restrict__ Bw,
    ushort* __restrict__ Cb, float* __restrict__ Cf, int bx, int by)
{
    extern __shared__ char smem[];
    const int tid = threadIdx.x;
    const int lane = tid & 63, wid = tid >> 6;
    const int wm = wid >> 1, wn = wid & 1;     // 4x2 wave grid; each wave 64x64 of C
    const int l15 = lane & 15, l4 = lane >> 4;
    const int brow = by * 256, bcol = bx * 128;

    // staging: linear LDS dest (tid*16 bytes); pre-swizzled global source col.
    // LDS(row, cb) holds global element-bytes cb ^ ((row&7)<<4).
    const int srow = tid >> 3;                                  // 0..63
    const int scol = ((tid & 7) * 8) ^ (((tid >> 3) & 7) << 3); // elements
    const uint sldso = (uint)tid * 16;

    f32x4 acc[4][4] = {};

    // one K-tile = A 32KB (4 gloads of rows j*64+srow) + B 16KB (2 gloads)
    #define STAGE6(bufo, k0)                                                         \
        do {                                                                         \
            _Pragma("unroll")                                                        \
            for (int j = 0; j < 4; ++j)                                              \
                gload_lds16(A + (size_t)(brow + j * 64 + srow) * D_ + ((k0) + scol), \
                            smem + (bufo) + j * 8192 + sldso);                       \
            _Pragma("unroll")                                                        \
            for (int j = 0; j < 2; ++j)                                              \
                gload_lds16(Bw + (size_t)(bcol + j * 64 + srow) * D_ + ((k0) + scol),\
                            smem + (bufo) + 32768u + j * 8192 + sldso);              \
        } while (0)

    // prologue: stage K-tiles 0 and 1
    STAGE6(0u, 0);
    STAGE6(49152u, 64);
    asm volatile("s_waitcnt vmcnt(6)" ::: "memory");
    SBAR;

    // read addressing: row = <base> + l15, col bytes (kk*64 + l4*16) ^ ((l15&7)<<4).
    // kk in the address register (XOR touches bit 6); 16-row frag steps (2048 B,
    // row&7 invariant) as ds_read immediates.
    const uint r7  = (uint)((l15 & 7) << 4);
    const uint ca0 = (uint)(l4 * 16) ^ r7;
    const uint ca1 = (uint)(64 + l4 * 16) ^ r7;
    const uint arow = (uint)(wm * 64 + l15) * 128u;
    const uint brw  = 32768u + (uint)(wn * 64 + l15) * 128u;
    const uint ldsbase = (uint)(size_t)smem;

    #pragma unroll 2
    for (int t = 0; t < 32; ++t) {
        const uint bo = ldsbase + (uint)(t & 1) * 49152u;
        const uint ab0 = bo + arow + ca0, ab1 = bo + arow + ca1;
        const uint bb0 = bo + brw + ca0,  bb1 = bo + brw + ca1;
        bf16x8 a0[8], b0[4], b1[4];
        // ---- P0: read A(m0-3) + B(n0-1); MFMA (m0-3, n0-1)
        a0[0] = dsr<0>(ab0);        a0[1] = dsr<0>(ab1);
        a0[2] = dsr<2048>(ab0);     a0[3] = dsr<2048>(ab1);
        a0[4] = dsr<4096>(ab0);     a0[5] = dsr<4096>(ab1);
        a0[6] = dsr<6144>(ab0);     a0[7] = dsr<6144>(ab1);
        b0[0] = dsr<0>(bb0);        b0[1] = dsr<0>(bb1);
        b0[2] = dsr<2048>(bb0);     b0[3] = dsr<2048>(bb1);
        SBAR;
        LGKM0;
        __builtin_amdgcn_s_setprio(1);
        #pragma unroll
        for (int ks = 0; ks < 2; ++ks)
            #pragma unroll
            for (int m = 0; m < 4; ++m)
                #pragma unroll
                for (int n = 0; n < 2; ++n)
                    acc[m][n] = __builtin_amdgcn_mfma_f32_16x16x32_bf16(
                        a0[m * 2 + ks], b0[n * 2 + ks], acc[m][n], 0, 0, 0);
        __builtin_amdgcn_sched_barrier(0);
        __builtin_amdgcn_s_setprio(0);
        SBAR;
        // ---- P1: read B(n2-3); MFMA (m0-3, n2-3); then stage K-tile t+2 into
        // buf[t&1] (all waves' reads of tile t issued pre-barrier, drained during MFMA)
        b1[0] = dsr<4096>(bb0);     b1[1] = dsr<4096>(bb1);
        b1[2] = dsr<6144>(bb0);     b1[3] = dsr<6144>(bb1);
        SBAR;
        LGKM0;
        __builtin_amdgcn_s_setprio(1);
        #pragma unroll
        for (int ks = 0; ks < 2; ++ks)
            #pragma unroll
            for (int m = 0; m < 4; ++m)
                #pragma unroll
                for (int n = 0; n < 2; ++n)
                    acc[m][2 + n] = __builtin_amdgcn_mfma_f32_16x16x32_bf16(
                        a0[m * 2 + ks], b1[n * 2 + ks], acc[m][2 + n], 0, 0, 0);
        __builtin_amdgcn_sched_barrier(0);
        __builtin_amdgcn_s_setprio(0);
        if (t <= 29) {
            const uint bo2 = (uint)(t & 1) * 49152u;
            STAGE6(bo2, (t + 2) * 64);
        }
        // boundary: own future loads stay in flight (counted), publish tile t+1
        if (t < 31) {
            if (t < 30) asm volatile("s_waitcnt vmcnt(6)" ::: "memory");
            else        asm volatile("s_waitcnt vmcnt(0)" ::: "memory");
            SBAR;
        }
    }
    #undef STAGE6

    #pragma unroll
    for (int m = 0; m < 4; ++m)
        #pragma unroll
        for (int n = 0; n < 4; ++n) {
            const int row = brow + wm * 64 + m * 16 + l4 * 4;
            const int col = bcol + wn * 64 + n * 16 + l15;
            #pragma unroll
            for (int r = 0; r < 4; ++r) {
                if (BF16OUT) Cb[(size_t)(row + r) * D_ + col] = f2bf(acc[m][n][r]);
                else         Cf[(size_t)(row + r) * D_ + col] = acc[m][n][r];
            }
        }
}

__global__ __launch_bounds__(512, 2) void gemm5_kernel(
    const ushort* __restrict__ xb, const ushort* __restrict__ xcb,
    const ushort* __restrict__ W6, ushort* __restrict__ Obuf)
{
    // bijective XCD swizzle over 1280 = 8 * 160 blocks; 256 tiles (16x16) per GEMM
    const int g = (blockIdx.z * 16 + blockIdx.y) * 16 + blockIdx.x;
    const int ns = (g & 7) * 160 + (g >> 3);
    const int z = ns >> 8, rem = ns & 255, by = rem >> 4, bx = rem & 15;
    const ushort* Aop = (z < 3) ? xb : xcb;
    gemm256_body<true>(Aop, W6 + (size_t)z * ((size_t)D_ * D_),
                       Obuf + (size_t)z * ((size_t)M_ * D_), nullptr, bx, by);
}

__global__ __launch_bounds__(512, 2) void gemm_out_kernel(
    const ushort* __restrict__ gated, const ushort* __restrict__ W6, float* __restrict__ out)
{
    // 256 blocks = 8 * 32
    const int g = blockIdx.y * 16 + blockIdx.x;
    const int ns = (g & 7) * 32 + (g >> 3);
    const int by = ns >> 4, bx = ns & 15;
    gemm256_body<false>(gated, W6 + (size_t)5 * ((size_t)D_ * D_), nullptr, out, bx, by);
}

// ---------- gamma = sigmoid(x_conv . Wg[h] + b_g[h]) — LDS-staged, 8 tokens/block ----------
__global__ __launch_bounds__(256) void gamma_kernel(
    const ushort* __restrict__ xcb, const float* __restrict__ Wg,
    const float* __restrict__ bg, float* __restrict__ gamma)
{
    __shared__ ushort xs[8 * D_];          // 32 KB
    const int tid = threadIdx.x;
    const int tok0 = blockIdx.x * 8;
    const uint4* gsrc = (const uint4*)(xcb + (size_t)tok0 * D_);
    #pragma unroll
    for (int j = 0; j < 8; ++j)
        ((uint4*)xs)[j * 256 + tid] = gsrc[j * 256 + tid];
    __syncthreads();
    const int tok = tid >> 5;              // 0..7
    const int h = (tid >> 1) & 15;
    const int half = tid & 1;
    const ushort* xr = xs + tok * D_ + half * 1024;
    const float* wr = Wg + (size_t)h * D_ + half * 1024;
    float acc = 0.f;
    #pragma unroll 4
    for (int i = 0; i < 1024; i += 8) {
        uint4 u = *(const uint4*)(xr + i);
        float4 w0 = *(const float4*)(wr + i);
        float4 w1 = *(const float4*)(wr + i + 4);
        acc += bflo(u.x) * w0.x + bfhi(u.x) * w0.y + bflo(u.y) * w0.z + bfhi(u.y) * w0.w;
        acc += bflo(u.z) * w1.x + bfhi(u.z) * w1.y + bflo(u.w) * w1.z + bfhi(u.w) * w1.w;
    }
    acc += __shfl_xor(acc, 1);
    if (!half) gamma[(size_t)(tok0 + tok) * H_ + h] = sigm(acc + bg[h]);
}

// ---------- bterm = sigmoid(igp + b_ig) * l2norm(k) * v ----------
__global__ __launch_bounds__(256) void bterm_kernel(
    const ushort* __restrict__ kb, const ushort* __restrict__ vb,
    const ushort* __restrict__ igb, const float* __restrict__ big,
    float* __restrict__ bt)
{
    const int token = blockIdx.x;
    const int tid = threadIdx.x;              // 16 threads per head (8 elems each)
    const int c0 = tid * 8;
    const size_t base = (size_t)token * D_ + c0;
    uint4 ku = *(const uint4*)(kb + base);
    uint4 vu = *(const uint4*)(vb + base);
    uint4 iu = *(const uint4*)(igb + base);
    float kf[8] = { bflo(ku.x), bfhi(ku.x), bflo(ku.y), bfhi(ku.y),
                    bflo(ku.z), bfhi(ku.z), bflo(ku.w), bfhi(ku.w) };
    float vf[8] = { bflo(vu.x), bfhi(vu.x), bflo(vu.y), bfhi(vu.y),
                    bflo(vu.z), bfhi(vu.z), bflo(vu.w), bfhi(vu.w) };
    float gf[8] = { bflo(iu.x), bfhi(iu.x), bflo(iu.y), bfhi(iu.y),
                    bflo(iu.z), bfhi(iu.z), bflo(iu.w), bfhi(iu.w) };
    float ss = 0.f;
    #pragma unroll
    for (int j = 0; j < 8; ++j) ss += kf[j] * kf[j];
    #pragma unroll
    for (int o = 1; o < 16; o <<= 1) ss += __shfl_xor(ss, o);
    const float sc = 1.f / fmaxf(sqrtf(ss), 1e-12f);
    float ot[8];
    #pragma unroll
    for (int j = 0; j < 8; ++j)
        ot[j] = sigm(gf[j] + big[c0 + j]) * (kf[j] * sc) * vf[j];
    float4 o0 = { ot[0], ot[1], ot[2], ot[3] };
    float4 o1 = { ot[4], ot[5], ot[6], ot[7] };
    *(float4*)(bt + base) = o0;
    *(float4*)(bt + base + 4) = o1;
}

// ---------- chunked parallel scan: mem[t] = gamma[t]*mem[t-1] + bt[t] ----------
__global__ __launch_bounds__(256) void scan1_kernel(
    const float* __restrict__ bt, const float* __restrict__ gam,
    float* __restrict__ Ab, float* __restrict__ Sb)
{
    const int c = blockIdx.x * 256 + threadIdx.x;
    const int ch = blockIdx.y, b = blockIdx.z;
    const int h = c >> 7;
    const float* g = gam + ((size_t)b * T_ + ch * CL_) * H_ + h;
    const float* p = bt + ((size_t)b * T_ + ch * CL_) * D_ + c;
    float a = 1.f, s = 0.f;
    #pragma unroll 8
    for (int i = 0; i < CL_; ++i) {
        const float gv = g[(size_t)i * H_];
        s = fmaf(gv, s, p[(size_t)i * D_]);
        a *= gv;
    }
    const size_t o = ((size_t)b * NC_ + ch) * D_ + c;
    Ab[o] = a; Sb[o] = s;
}

__global__ __launch_bounds__(256) void scan2_kernel(
    const float* __restrict__ Ab, const float* __restrict__ Sb, float* __restrict__ carry)
{
    const int idx = blockIdx.x * 256 + threadIdx.x;   // b*D + c
    const int b = idx >> 11, c = idx & (D_ - 1);
    float run = 0.f;
    #pragma unroll
    for (int ch = 0; ch < NC_; ++ch) {
        const size_t o = ((size_t)b * NC_ + ch) * D_ + c;
        carry[o] = run;
        run = fmaf(Ab[o], run, Sb[o]);
    }
}

__global__ __launch_bounds__(256) void scan3_kernel(
    float* __restrict__ bt, const float* __restrict__ gam, const float* __restrict__ carry)
{
    const int c = blockIdx.x * 256 + threadIdx.x;
    const int ch = blockIdx.y, b = blockIdx.z;
    const int h = c >> 7;
    const float* g = gam + ((size_t)b * T_ + ch * CL_) * H_ + h;
    float* p = bt + ((size_t)b * T_ + ch * CL_) * D_ + c;
    float m = carry[((size_t)b * NC_ + ch) * D_ + c];
    #pragma unroll 8
    for (int i = 0; i < CL_; ++i) {
        m = fmaf(g[(size_t)i * H_], m, p[(size_t)i * D_]);
        p[(size_t)i * D_] = m;
    }
}

// ---------- GN(mem)*l2norm(q) -> GN -> *sigmoid(og) -> bf16; also rnn_state ----------
__global__ __launch_bounds__(256) void norm_kernel(
    const float* __restrict__ mem, const ushort* __restrict__ qb,
    const ushort* __restrict__ ogb, const float* __restrict__ bog,
    const float* __restrict__ mnw, const float* __restrict__ mnb,
    const float* __restrict__ gnw, const float* __restrict__ gnb,
    ushort* __restrict__ gated, float* __restrict__ rnn)
{
    const int token = blockIdx.x;
    const int tid = threadIdx.x;
    const int c0 = tid * 8;
    const size_t base = (size_t)token * D_ + c0;
    float mm[8];
    { float4 a = *(const float4*)(mem + base); float4 b2 = *(const float4*)(mem + base + 4);
      mm[0]=a.x; mm[1]=a.y; mm[2]=a.z; mm[3]=a.w; mm[4]=b2.x; mm[5]=b2.y; mm[6]=b2.z; mm[7]=b2.w; }
    float s1 = 0.f, s2 = 0.f;
    #pragma unroll
    for (int j = 0; j < 8; ++j) { s1 += mm[j]; s2 += mm[j] * mm[j]; }
    #pragma unroll
    for (int o = 1; o < 16; o <<= 1) { s1 += __shfl_xor(s1, o); s2 += __shfl_xor(s2, o); }
    const float mu = s1 * (1.f / 128.f);
    const float inv = 1.f / sqrtf(fmaxf(s2 * (1.f / 128.f) - mu * mu, 0.f) + EPS_);
    uint4 qu = *(const uint4*)(qb + base);
    float qf[8] = { bflo(qu.x), bfhi(qu.x), bflo(qu.y), bfhi(qu.y),
                    bflo(qu.z), bfhi(qu.z), bflo(qu.w), bfhi(qu.w) };
    float qs = 0.f;
    #pragma unroll
    for (int j = 0; j < 8; ++j) qs += qf[j] * qf[j];
    #pragma unroll
    for (int o = 1; o < 16; o <<= 1) qs += __shfl_xor(qs, o);
    const float qsc = 1.f / fmaxf(sqrtf(qs), 1e-12f);
    float ov[8]; float t1 = 0.f, t2 = 0.f;
    #pragma unroll
    for (int j = 0; j < 8; ++j) {
        const float mn = (mm[j] - mu) * inv * mnw[c0 + j] + mnb[c0 + j];
        ov[j] = mn * (qf[j] * qsc);
        t1 += ov[j]; t2 += ov[j] * ov[j];
    }
    #pragma unroll
    for (int o = 1; o < 16; o <<= 1) { t1 += __shfl_xor(t1, o); t2 += __shfl_xor(t2, o); }
    const float mu2 = t1 * (1.f / 128.f);
    const float inv2 = 1.f / sqrtf(fmaxf(t2 * (1.f / 128.f) - mu2 * mu2, 0.f) + EPS_);
    uint4 ou = *(const uint4*)(ogb + base);
    float of[8] = { bflo(ou.x), bfhi(ou.x), bflo(ou.y), bfhi(ou.y),
                    bflo(ou.z), bfhi(ou.z), bflo(ou.w), bfhi(ou.w) };
    uint pk[4];
    #pragma unroll
    for (int j2 = 0; j2 < 4; ++j2) {
        const int e0 = 2 * j2, e1 = 2 * j2 + 1;
        float g0 = ((ov[e0] - mu2) * inv2 * gnw[c0 + e0] + gnb[c0 + e0]) * sigm(of[e0] + bog[c0 + e0]);
        float g1 = ((ov[e1] - mu2) * inv2 * gnw[c0 + e1] + gnb[c0 + e1]) * sigm(of[e1] + bog[c0 + e1]);
        pk[j2] = (uint)f2bf(g0) | ((uint)f2bf(g1) << 16);
    }
    uint4 st = { pk[0], pk[1], pk[2], pk[3] };
    *(uint4*)(gated + base) = st;
    if ((token & (T_ - 1)) == T_ - 1) {       // t == T-1: raw mem -> next_rnn_state
        float* r = rnn + (size_t)(token >> 11) * D_ + c0;
        float4 r0 = { mm[0], mm[1], mm[2], mm[3] };
        float4 r1 = { mm[4], mm[5], mm[6], mm[7] };
        *(float4*)r = r0; *(float4*)(r + 4) = r1;
    }
}

// ---------- conv cache: x^T last K-1 timesteps ----------
__global__ __launch_bounds__(256) void cache_kernel(const float* __restrict__ x, float* __restrict__ out)
{
    const int idx = blockIdx.x * 256 + threadIdx.x;  // B*D*3
    if (idx >= B_ * D_ * 3) return;
    const int b = idx / (D_ * 3);
    const int rem = idx - b * (D_ * 3);
    const int c = rem / 3;
    const int j = rem - c * 3;
    out[idx] = x[((size_t)b * T_ + (T_ - 3 + j)) * D_ + c];
}

extern "C" void kernel_launch(void* const* d_in, const int* in_sizes, int n_in,
                              void* d_out, int out_size, void* d_ws, size_t ws_size,
                              hipStream_t stream)
{
    const float* x   = (const float*)d_in[0];
    const float* Wq  = (const float*)d_in[1];
    const float* Wk  = (const float*)d_in[2];
    const float* Wv  = (const float*)d_in[3];
    const float* Wo  = (const float*)d_in[4];
    const float* cw  = (const float*)d_in[5];
    const float* cb  = (const float*)d_in[6];
    const float* Wig = (const float*)d_in[7];
    const float* big = (const float*)d_in[8];
    const float* Wog = (const float*)d_in[9];
    const float* bog = (const float*)d_in[10];
    const float* Wg  = (const float*)d_in[11];
    const float* bg  = (const float*)d_in[12];
    const float* gnw = (const float*)d_in[13];
    const float* gnb = (const float*)d_in[14];
    const float* mnw = (const float*)d_in[15];
    const float* mnb = (const float*)d_in[16];

    char* ws = (char*)d_ws;
    ushort* W6   = (ushort*)ws;                                         // 50,331,648 B
    ushort* xb   = (ushort*)(ws + 50331648);                            // 16,777,216
    ushort* xcb  = (ushort*)(ws + 50331648 + 16777216);                 // 16,777,216
    ushort* Obuf = (ushort*)(ws + 50331648 + 2 * 16777216);             // 5 x 16,777,216
    float*  gam  = (float*)(ws + 50331648 + 7 * 16777216);              // 262,144
    float*  bt   = (float*)(ws + 50331648 + 7 * 16777216 + 262144);     // 33,554,432

    ushort* q    = Obuf;
    ushort* k    = Obuf + (size_t)M_ * D_;
    ushort* v    = Obuf + 2 * (size_t)M_ * D_;
    ushort* igp  = Obuf + 3 * (size_t)M_ * D_;
    ushort* ogp  = Obuf + 4 * (size_t)M_ * D_;
    ushort* gated = k;                         // k dead after bterm_kernel
    float*  Ab   = (float*)v;                  // v dead after bterm_kernel (1.5MB << 16.8MB)
    float*  Sb   = Ab + (size_t)B_ * NC_ * D_;
    float*  carry= Sb + (size_t)B_ * NC_ * D_;

    float* out  = (float*)d_out;
    float* rnn  = out + (size_t)M_ * D_;
    float* cach = rnn + B_ * D_;

    (void)hipFuncSetAttribute((const void*)gemm5_kernel,
                              hipFuncAttributeMaxDynamicSharedMemorySize, 98304);
    (void)hipFuncSetAttribute((const void*)gemm_out_kernel,
                              hipFuncAttributeMaxDynamicSharedMemorySize, 98304);

    cvtw_kernel<<<dim3(4096, 6), 256, 0, stream>>>(Wq, Wk, Wv, Wig, Wog, Wo, W6);
    conv_kernel<<<dim3(M_ * D_ / 256), 256, 0, stream>>>(x, cw, cb, xb, xcb);
    gemm5_kernel<<<dim3(16, 16, 5), 512, 98304, stream>>>(xb, xcb, W6, Obuf);
    gamma_kernel<<<dim3(M_ / 8), 256, 0, stream>>>(xcb, Wg, bg, gam);
    bterm_kernel<<<dim3(M_), 256, 0, stream>>>(k, v, igp, big, bt);
    scan1_kernel<<<dim3(8, NC_, 2), 256, 0, stream>>>(bt, gam, Ab, Sb);
    scan2_kernel<<<dim3(16), 256, 0, stream>>>(Ab, Sb, carry);
    scan3_kernel<<<dim3(8, NC_, 2), 256, 0, stream>>>(bt, gam, carry);
    norm_kernel<<<dim3(M_), 256, 0, stream>>>(bt, q, ogp, bog, mnw, mnb, gnw, gnb, gated, rnn);
    gemm_out_kernel<<<dim3(16, 16), 512, 98304, stream>>>(gated, W6, out);
    cache_kernel<<<dim3(48), 256, 0, stream>>>(x, cach);
}

// Round 6
// 384.607 us; speedup vs baseline: 1.5352x; 1.0260x over previous
//
#include <hip/hip_runtime.h>
#include <math.h>

#define B_ 2
#define T_ 2048
#define D_ 2048
#define H_ 16
#define M_ 4096          // B*T
#define TD_ (T_ * D_)
#define EPS_ 1e-5f
#define NC_ 32           // scan chunks
#define CL_ 64           // scan chunk length

typedef __bf16 bf16x8 __attribute__((ext_vector_type(8)));
typedef float f32x4 __attribute__((ext_vector_type(4)));

__device__ __forceinline__ float sigm(float z) { return 1.f / (1.f + __expf(-z)); }

__device__ __forceinline__ ushort f2bf(float f) {  // RNE f32 -> bf16 bits
    union { float f; uint u; } x; x.f = f;
    uint r = x.u + 0x7fffu + ((x.u >> 16) & 1u);
    return (ushort)(r >> 16);
}
__device__ __forceinline__ float bflo(uint u) { union { uint u; float f; } x; x.u = u << 16; return x.f; }
__device__ __forceinline__ float bfhi(uint u) { union { uint u; float f; } x; x.u = u & 0xffff0000u; return x.f; }

__device__ __forceinline__ void gload_lds16(const void* g, void* l) {
    __builtin_amdgcn_global_load_lds((const __attribute__((address_space(1))) void*)g,
                                     (__attribute__((address_space(3))) void*)l, 16, 0, 0);
}

template <int IMM>
__device__ __forceinline__ bf16x8 dsr(uint addr) {
    int4 d;
    asm volatile("ds_read_b128 %0, %1 offset:%2" : "=v"(d) : "v"(addr), "n"(IMM));
    return __builtin_bit_cast(bf16x8, d);
}
#define SCB   __builtin_amdgcn_sched_barrier(0)
#define SBAR  __builtin_amdgcn_s_barrier()

// ---------- weights f32 -> bf16 (order: Wq,Wk,Wv,Wig,Wog,Wo) ----------
__global__ __launch_bounds__(256) void cvtw_kernel(
    const float* __restrict__ Wq, const float* __restrict__ Wk, const float* __restrict__ Wv,
    const float* __restrict__ Wig, const float* __restrict__ Wog, const float* __restrict__ Wo,
    ushort* __restrict__ W6)
{
    const int z = blockIdx.y;
    const float* src = z == 0 ? Wq : z == 1 ? Wk : z == 2 ? Wv : z == 3 ? Wig : z == 4 ? Wog : Wo;
    const int i4 = (blockIdx.x * 256 + threadIdx.x) * 4;
    float4 f = *(const float4*)(src + i4);
    ushort4 o; o.x = f2bf(f.x); o.y = f2bf(f.y); o.z = f2bf(f.z); o.w = f2bf(f.w);
    *(ushort4*)(W6 + (size_t)z * ((size_t)D_ * D_) + i4) = o;
}

// ---------- causal depthwise conv (K=4) + silu; emits x as bf16 + conv cache ----------
__global__ __launch_bounds__(256) void conv_kernel(
    const float* __restrict__ x, const float* __restrict__ cw, const float* __restrict__ cb,
    ushort* __restrict__ xb, ushort* __restrict__ xcb, float* __restrict__ cach)
{
    const int idx = blockIdx.x * 256 + threadIdx.x;
    const int c = idx & (D_ - 1);
    const int t = (idx >> 11) & (T_ - 1);
    const int b = idx >> 22;
    const float* w = cw + c * 4;
    const float x3 = x[idx];
    float a = cb[c] + w[3] * x3;
    if (t >= 1) a += w[2] * x[idx - D_];
    if (t >= 2) a += w[1] * x[idx - 2 * D_];
    if (t >= 3) a += w[0] * x[idx - 3 * D_];
    xb[idx] = f2bf(x3);
    xcb[idx] = f2bf(a * sigm(a));
    if (t >= T_ - 3) cach[((size_t)b * D_ + c) * 3 + (t - (T_ - 3))] = x3;   // x^T last K-1
}

// ---------- 256x128 GEMM: C[M,N] = A[M,K] * W[N,K]^T  (bf16 in) ----------
// 512 thr (8 waves 4x2), BK=64, LDS 96KB double-buffered (48KB/buf: A 32KB, B 16KB),
// 3-bit row XOR-swizzle (byte ^= (row&7)<<4) on staging source + ds_read addr.
// One barrier per K-tile: all 16 ds_reads hoisted to tile top (b1 last),
// lgkmcnt(4) -> P0 MFMA, lgkmcnt(0) -> P1 MFMA, stage t+2, vmcnt(6), s_barrier.
template <bool BF16OUT>
__device__ __forceinline__ void gemm256_body(
    const ushort* __restrict__ A, const ushort* __restrict__ Bw,
    ushort* __restrict__ Cb, float* __restrict__ Cf, int bx, int by)
{
    extern __shared__ char smem[];
    const int tid = threadIdx.x;
    const int lane = tid & 63, wid = tid >> 6;
    const int wm = wid >> 1, wn = wid & 1;     // 4x2 wave grid; each wave 64x64 of C
    const int l15 = lane & 15, l4 = lane >> 4;
    const int brow = by * 256, bcol = bx * 128;

    // staging: linear LDS dest (tid*16 bytes); pre-swizzled global source col.
    // LDS(row, cb) holds global element-bytes cb ^ ((row&7)<<4).
    const int srow = tid >> 3;                                  // 0..63
    const int scol = ((tid & 7) * 8) ^ (((tid >> 3) & 7) << 3); // elements
    const uint sldso = (uint)tid * 16;

    f32x4 acc[4][4] = {};

    // one K-tile = A 32KB (4 gloads of rows j*64+srow) + B 16KB (2 gloads)
    #define STAGE6(bufo, k0)                                                         \
        do {                                                                         \
            _Pragma("unroll")                                                        \
            for (int j = 0; j < 4; ++j)                                              \
                gload_lds16(A + (size_t)(brow + j * 64 + srow) * D_ + ((k0) + scol), \
                            smem + (bufo) + j * 8192 + sldso);                       \
            _Pragma("unroll")                                                        \
            for (int j = 0; j < 2; ++j)                                              \
                gload_lds16(Bw + (size_t)(bcol + j * 64 + srow) * D_ + ((k0) + scol),\
                            smem + (bufo) + 32768u + j * 8192 + sldso);              \
        } while (0)

    // prologue: stage K-tiles 0 and 1
    STAGE6(0u, 0);
    STAGE6(49152u, 64);
    asm volatile("s_waitcnt vmcnt(6)" ::: "memory");
    SBAR; SCB;

    // read addressing: row = <base> + l15, col bytes (kk*64 + l4*16) ^ ((l15&7)<<4).
    const uint r7  = (uint)((l15 & 7) << 4);
    const uint ca0 = (uint)(l4 * 16) ^ r7;
    const uint ca1 = (uint)(64 + l4 * 16) ^ r7;
    const uint arow = (uint)(wm * 64 + l15) * 128u;
    const uint brw  = 32768u + (uint)(wn * 64 + l15) * 128u;
    const uint ldsbase = (uint)(size_t)smem;

    #pragma unroll 2
    for (int t = 0; t < 32; ++t) {
        const uint bo = ldsbase + (uint)(t & 1) * 49152u;
        const uint ab0 = bo + arow + ca0, ab1 = bo + arow + ca1;
        const uint bb0 = bo + brw + ca0,  bb1 = bo + brw + ca1;
        bf16x8 a0[8], b0[4], b1[4];
        // all reads for this tile, b1 last
        a0[0] = dsr<0>(ab0);        a0[1] = dsr<0>(ab1);
        a0[2] = dsr<2048>(ab0);     a0[3] = dsr<2048>(ab1);
        a0[4] = dsr<4096>(ab0);     a0[5] = dsr<4096>(ab1);
        a0[6] = dsr<6144>(ab0);     a0[7] = dsr<6144>(ab1);
        b0[0] = dsr<0>(bb0);        b0[1] = dsr<0>(bb1);
        b0[2] = dsr<2048>(bb0);     b0[3] = dsr<2048>(bb1);
        b1[0] = dsr<4096>(bb0);     b1[1] = dsr<4096>(bb1);
        b1[2] = dsr<6144>(bb0);     b1[3] = dsr<6144>(bb1);
        // P0: wait a0,b0 (4 outstanding = b1), MFMA (m0-3, n0-1); b1 completes in shadow
        asm volatile("s_waitcnt lgkmcnt(4)" ::: "memory");
        SCB;
        __builtin_amdgcn_s_setprio(1);
        #pragma unroll
        for (int ks = 0; ks < 2; ++ks)
            #pragma unroll
            for (int m = 0; m < 4; ++m)
                #pragma unroll
                for (int n = 0; n < 2; ++n)
                    acc[m][n] = __builtin_amdgcn_mfma_f32_16x16x32_bf16(
                        a0[m * 2 + ks], b0[n * 2 + ks], acc[m][n], 0, 0, 0);
        SCB;
        __builtin_amdgcn_s_setprio(0);
        // P1: wait b1 (likely no-op), MFMA (m0-3, n2-3)
        asm volatile("s_waitcnt lgkmcnt(0)" ::: "memory");
        SCB;
        __builtin_amdgcn_s_setprio(1);
        #pragma unroll
        for (int ks = 0; ks < 2; ++ks)
            #pragma unroll
            for (int m = 0; m < 4; ++m)
                #pragma unroll
                for (int n = 0; n < 2; ++n)
                    acc[m][2 + n] = __builtin_amdgcn_mfma_f32_16x16x32_bf16(
                        a0[m * 2 + ks], b1[n * 2 + ks], acc[m][2 + n], 0, 0, 0);
        SCB;
        __builtin_amdgcn_s_setprio(0);
        // stage K-tile t+2 into buf[t&1] (this wave's reads drained; others' reads
        // completed ~300cy post-barrier << staged data return ~650cy post-barrier)
        if (t <= 29) {
            const uint bo2 = (uint)(t & 1) * 49152u;
            STAGE6(bo2, (t + 2) * 64);
        }
        // boundary: counted drain (own future loads stay in flight), publish tile t+1
        if (t < 31) {
            if (t < 30) asm volatile("s_waitcnt vmcnt(6)" ::: "memory");
            else        asm volatile("s_waitcnt vmcnt(0)" ::: "memory");
            SBAR; SCB;
        }
    }
    #undef STAGE6

    #pragma unroll
    for (int m = 0; m < 4; ++m)
        #pragma unroll
        for (int n = 0; n < 4; ++n) {
            const int row = brow + wm * 64 + m * 16 + l4 * 4;
            const int col = bcol + wn * 64 + n * 16 + l15;
            #pragma unroll
            for (int r = 0; r < 4; ++r) {
                if (BF16OUT) Cb[(size_t)(row + r) * D_ + col] = f2bf(acc[m][n][r]);
                else         Cf[(size_t)(row + r) * D_ + col] = acc[m][n][r];
            }
        }
}

__global__ __launch_bounds__(512, 2) void gemm5_kernel(
    const ushort* __restrict__ xb, const ushort* __restrict__ xcb,
    const ushort* __restrict__ W6, ushort* __restrict__ Obuf)
{
    // bijective XCD swizzle over 1280 = 8 * 160 blocks; 256 tiles (16x16) per GEMM
    const int g = (blockIdx.z * 16 + blockIdx.y) * 16 + blockIdx.x;
    const int ns = (g & 7) * 160 + (g >> 3);
    const int z = ns >> 8, rem = ns & 255, by = rem >> 4, bx = rem & 15;
    const ushort* Aop = (z < 3) ? xb : xcb;
    gemm256_body<true>(Aop, W6 + (size_t)z * ((size_t)D_ * D_),
                       Obuf + (size_t)z * ((size_t)M_ * D_), nullptr, bx, by);
}

__global__ __launch_bounds__(512, 2) void gemm_out_kernel(
    const ushort* __restrict__ gated, const ushort* __restrict__ W6, float* __restrict__ out)
{
    // 256 blocks = 8 * 32
    const int g = blockIdx.y * 16 + blockIdx.x;
    const int ns = (g & 7) * 32 + (g >> 3);
    const int by = ns >> 4, bx = ns & 15;
    gemm256_body<false>(gated, W6 + (size_t)5 * ((size_t)D_ * D_), nullptr, out, bx, by);
}

// ---------- gamma = sigmoid(x_conv . Wg[h] + b_g[h]) — LDS-staged, 8 tokens/block ----------
__global__ __launch_bounds__(256) void gamma_kernel(
    const ushort* __restrict__ xcb, const float* __restrict__ Wg,
    const float* __restrict__ bg, float* __restrict__ gamma)
{
    __shared__ ushort xs[8 * D_];          // 32 KB
    const int tid = threadIdx.x;
    const int tok0 = blockIdx.x * 8;
    const uint4* gsrc = (const uint4*)(xcb + (size_t)tok0 * D_);
    #pragma unroll
    for (int j = 0; j < 8; ++j)
        ((uint4*)xs)[j * 256 + tid] = gsrc[j * 256 + tid];
    __syncthreads();
    const int tok = tid >> 5;              // 0..7
    const int h = (tid >> 1) & 15;
    const int half = tid & 1;
    const ushort* xr = xs + tok * D_ + half * 1024;
    const float* wr = Wg + (size_t)h * D_ + half * 1024;
    float acc = 0.f;
    #pragma unroll 4
    for (int i = 0; i < 1024; i += 8) {
        uint4 u = *(const uint4*)(xr + i);
        float4 w0 = *(const float4*)(wr + i);
        float4 w1 = *(const float4*)(wr + i + 4);
        acc += bflo(u.x) * w0.x + bfhi(u.x) * w0.y + bflo(u.y) * w0.z + bfhi(u.y) * w0.w;
        acc += bflo(u.z) * w1.x + bfhi(u.z) * w1.y + bflo(u.w) * w1.z + bfhi(u.w) * w1.w;
    }
    acc += __shfl_xor(acc, 1);
    if (!half) gamma[(size_t)(tok0 + tok) * H_ + h] = sigm(acc + bg[h]);
}

// ---------- bterm = sigmoid(igp + b_ig) * l2norm(k) * v ----------
__global__ __launch_bounds__(256) void bterm_kernel(
    const ushort* __restrict__ kb, const ushort* __restrict__ vb,
    const ushort* __restrict__ igb, const float* __restrict__ big,
    float* __restrict__ bt)
{
    const int token = blockIdx.x;
    const int tid = threadIdx.x;              // 16 threads per head (8 elems each)
    const int c0 = tid * 8;
    const size_t base = (size_t)token * D_ + c0;
    uint4 ku = *(const uint4*)(kb + base);
    uint4 vu = *(const uint4*)(vb + base);
    uint4 iu = *(const uint4*)(igb + base);
    float kf[8] = { bflo(ku.x), bfhi(ku.x), bflo(ku.y), bfhi(ku.y),
                    bflo(ku.z), bfhi(ku.z), bflo(ku.w), bfhi(ku.w) };
    float vf[8] = { bflo(vu.x), bfhi(vu.x), bflo(vu.y), bfhi(vu.y),
                    bflo(vu.z), bfhi(vu.z), bflo(vu.w), bfhi(vu.w) };
    float gf[8] = { bflo(iu.x), bfhi(iu.x), bflo(iu.y), bfhi(iu.y),
                    bflo(iu.z), bfhi(iu.z), bflo(iu.w), bfhi(iu.w) };
    float ss = 0.f;
    #pragma unroll
    for (int j = 0; j < 8; ++j) ss += kf[j] * kf[j];
    #pragma unroll
    for (int o = 1; o < 16; o <<= 1) ss += __shfl_xor(ss, o);
    const float sc = 1.f / fmaxf(sqrtf(ss), 1e-12f);
    float ot[8];
    #pragma unroll
    for (int j = 0; j < 8; ++j)
        ot[j] = sigm(gf[j] + big[c0 + j]) * (kf[j] * sc) * vf[j];
    float4 o0 = { ot[0], ot[1], ot[2], ot[3] };
    float4 o1 = { ot[4], ot[5], ot[6], ot[7] };
    *(float4*)(bt + base) = o0;
    *(float4*)(bt + base + 4) = o1;
}

// ---------- chunked parallel scan: mem[t] = gamma[t]*mem[t-1] + bt[t] ----------
__global__ __launch_bounds__(256) void scan1_kernel(
    const float* __restrict__ bt, const float* __restrict__ gam,
    float* __restrict__ Ab, float* __restrict__ Sb)
{
    const int c = blockIdx.x * 256 + threadIdx.x;
    const int ch = blockIdx.y, b = blockIdx.z;
    const int h = c >> 7;
    const float* g = gam + ((size_t)b * T_ + ch * CL_) * H_ + h;
    const float* p = bt + ((size_t)b * T_ + ch * CL_) * D_ + c;
    float a = 1.f, s = 0.f;
    #pragma unroll 8
    for (int i = 0; i < CL_; ++i) {
        const float gv = g[(size_t)i * H_];
        s = fmaf(gv, s, p[(size_t)i * D_]);
        a *= gv;
    }
    const size_t o = ((size_t)b * NC_ + ch) * D_ + c;
    Ab[o] = a; Sb[o] = s;
}

__global__ __launch_bounds__(256) void scan2_kernel(
    const float* __restrict__ Ab, const float* __restrict__ Sb, float* __restrict__ carry)
{
    const int idx = blockIdx.x * 256 + threadIdx.x;   // b*D + c
    const int b = idx >> 11, c = idx & (D_ - 1);
    float run = 0.f;
    #pragma unroll
    for (int ch = 0; ch < NC_; ++ch) {
        const size_t o = ((size_t)b * NC_ + ch) * D_ + c;
        carry[o] = run;
        run = fmaf(Ab[o], run, Sb[o]);
    }
}

__global__ __launch_bounds__(256) void scan3_kernel(
    float* __restrict__ bt, const float* __restrict__ gam, const float* __restrict__ carry)
{
    const int c = blockIdx.x * 256 + threadIdx.x;
    const int ch = blockIdx.y, b = blockIdx.z;
    const int h = c >> 7;
    const float* g = gam + ((size_t)b * T_ + ch * CL_) * H_ + h;
    float* p = bt + ((size_t)b * T_ + ch * CL_) * D_ + c;
    float m = carry[((size_t)b * NC_ + ch) * D_ + c];
    #pragma unroll 8
    for (int i = 0; i < CL_; ++i) {
        m = fmaf(g[(size_t)i * H_], m, p[(size_t)i * D_]);
        p[(size_t)i * D_] = m;
    }
}

// ---------- GN(mem)*l2norm(q) -> GN -> *sigmoid(og) -> bf16; also rnn_state ----------
__global__ __launch_bounds__(256) void norm_kernel(
    const float* __restrict__ mem, const ushort* __restrict__ qb,
    const ushort* __restrict__ ogb, const float* __restrict__ bog,
    const float* __restrict__ mnw, const float* __restrict__ mnb,
    const float* __restrict__ gnw, const float* __restrict__ gnb,
    ushort* __restrict__ gated, float* __restrict__ rnn)
{
    const int token = blockIdx.x;
    const int tid = threadIdx.x;
    const int c0 = tid * 8;
    const size_t base = (size_t)token * D_ + c0;
    float mm[8];
    { float4 a = *(const float4*)(mem + base); float4 b2 = *(const float4*)(mem + base + 4);
      mm[0]=a.x; mm[1]=a.y; mm[2]=a.z; mm[3]=a.w; mm[4]=b2.x; mm[5]=b2.y; mm[6]=b2.z; mm[7]=b2.w; }
    float s1 = 0.f, s2 = 0.f;
    #pragma unroll
    for (int j = 0; j < 8; ++j) { s1 += mm[j]; s2 += mm[j] * mm[j]; }
    #pragma unroll
    for (int o = 1; o < 16; o <<= 1) { s1 += __shfl_xor(s1, o); s2 += __shfl_xor(s2, o); }
    const float mu = s1 * (1.f / 128.f);
    const float inv = 1.f / sqrtf(fmaxf(s2 * (1.f / 128.f) - mu * mu, 0.f) + EPS_);
    uint4 qu = *(const uint4*)(qb + base);
    float qf[8] = { bflo(qu.x), bfhi(qu.x), bflo(qu.y), bfhi(qu.y),
                    bflo(qu.z), bfhi(qu.z), bflo(qu.w), bfhi(qu.w) };
    float qs = 0.f;
    #pragma unroll
    for (int j = 0; j < 8; ++j) qs += qf[j] * qf[j];
    #pragma unroll
    for (int o = 1; o < 16; o <<= 1) qs += __shfl_xor(qs, o);
    const float qsc = 1.f / fmaxf(sqrtf(qs), 1e-12f);
    float ov[8]; float t1 = 0.f, t2 = 0.f;
    #pragma unroll
    for (int j = 0; j < 8; ++j) {
        const float mn = (mm[j] - mu) * inv * mnw[c0 + j] + mnb[c0 + j];
        ov[j] = mn * (qf[j] * qsc);
        t1 += ov[j]; t2 += ov[j] * ov[j];
    }
    #pragma unroll
    for (int o = 1; o < 16; o <<= 1) { t1 += __shfl_xor(t1, o); t2 += __shfl_xor(t2, o); }
    const float mu2 = t1 * (1.f / 128.f);
    const float inv2 = 1.f / sqrtf(fmaxf(t2 * (1.f / 128.f) - mu2 * mu2, 0.f) + EPS_);
    uint4 ou = *(const uint4*)(ogb + base);
    float of[8] = { bflo(ou.x), bfhi(ou.x), bflo(ou.y), bfhi(ou.y),
                    bflo(ou.z), bfhi(ou.z), bflo(ou.w), bfhi(ou.w) };
    uint pk[4];
    #pragma unroll
    for (int j2 = 0; j2 < 4; ++j2) {
        const int e0 = 2 * j2, e1 = 2 * j2 + 1;
        float g0 = ((ov[e0] - mu2) * inv2 * gnw[c0 + e0] + gnb[c0 + e0]) * sigm(of[e0] + bog[c0 + e0]);
        float g1 = ((ov[e1] - mu2) * inv2 * gnw[c0 + e1] + gnb[c0 + e1]) * sigm(of[e1] + bog[c0 + e1]);
        pk[j2] = (uint)f2bf(g0) | ((uint)f2bf(g1) << 16);
    }
    uint4 st = { pk[0], pk[1], pk[2], pk[3] };
    *(uint4*)(gated + base) = st;
    if ((token & (T_ - 1)) == T_ - 1) {       // t == T-1: raw mem -> next_rnn_state
        float* r = rnn + (size_t)(token >> 11) * D_ + c0;
        float4 r0 = { mm[0], mm[1], mm[2], mm[3] };
        float4 r1 = { mm[4], mm[5], mm[6], mm[7] };
        *(float4*)r = r0; *(float4*)(r + 4) = r1;
    }
}

extern "C" void kernel_launch(void* const* d_in, const int* in_sizes, int n_in,
                              void* d_out, int out_size, void* d_ws, size_t ws_size,
                              hipStream_t stream)
{
    const float* x   = (const float*)d_in[0];
    const float* Wq  = (const float*)d_in[1];
    const float* Wk  = (const float*)d_in[2];
    const float* Wv  = (const float*)d_in[3];
    const float* Wo  = (const float*)d_in[4];
    const float* cw  = (const float*)d_in[5];
    const float* cb  = (const float*)d_in[6];
    const float* Wig = (const float*)d_in[7];
    const float* big = (const float*)d_in[8];
    const float* Wog = (const float*)d_in[9];
    const float* bog = (const float*)d_in[10];
    const float* Wg  = (const float*)d_in[11];
    const float* bg  = (const float*)d_in[12];
    const float* gnw = (const float*)d_in[13];
    const float* gnb = (const float*)d_in[14];
    const float* mnw = (const float*)d_in[15];
    const float* mnb = (const float*)d_in[16];

    char* ws = (char*)d_ws;
    ushort* W6   = (ushort*)ws;                                         // 50,331,648 B
    ushort* xb   = (ushort*)(ws + 50331648);                            // 16,777,216
    ushort* xcb  = (ushort*)(ws + 50331648 + 16777216);                 // 16,777,216
    ushort* Obuf = (ushort*)(ws + 50331648 + 2 * 16777216);             // 5 x 16,777,216
    float*  gam  = (float*)(ws + 50331648 + 7 * 16777216);              // 262,144
    float*  bt   = (float*)(ws + 50331648 + 7 * 16777216 + 262144);     // 33,554,432

    ushort* q    = Obuf;
    ushort* k    = Obuf + (size_t)M_ * D_;
    ushort* v    = Obuf + 2 * (size_t)M_ * D_;
    ushort* igp  = Obuf + 3 * (size_t)M_ * D_;
    ushort* ogp  = Obuf + 4 * (size_t)M_ * D_;
    ushort* gated = k;                         // k dead after bterm_kernel
    float*  Ab   = (float*)v;                  // v dead after bterm_kernel (1.5MB << 16.8MB)
    float*  Sb   = Ab + (size_t)B_ * NC_ * D_;
    float*  carry= Sb + (size_t)B_ * NC_ * D_;

    float* out  = (float*)d_out;
    float* rnn  = out + (size_t)M_ * D_;
    float* cach = rnn + B_ * D_;

    (void)hipFuncSetAttribute((const void*)gemm5_kernel,
                              hipFuncAttributeMaxDynamicSharedMemorySize, 98304);
    (void)hipFuncSetAttribute((const void*)gemm_out_kernel,
                              hipFuncAttributeMaxDynamicSharedMemorySize, 98304);

    cvtw_kernel<<<dim3(4096, 6), 256, 0, stream>>>(Wq, Wk, Wv, Wig, Wog, Wo, W6);
    conv_kernel<<<dim3(M_ * D_ / 256), 256, 0, stream>>>(x, cw, cb, xb, xcb, cach);
    gemm5_kernel<<<dim3(16, 16, 5), 512, 98304, stream>>>(xb, xcb, W6, Obuf);
    gamma_kernel<<<dim3(M_ / 8), 256, 0, stream>>>(xcb, Wg, bg, gam);
    bterm_kernel<<<dim3(M_), 256, 0, stream>>>(k, v, igp, big, bt);
    scan1_kernel<<<dim3(8, NC_, 2), 256, 0, stream>>>(bt, gam, Ab, Sb);
    scan2_kernel<<<dim3(16), 256, 0, stream>>>(Ab, Sb, carry);
    scan3_kernel<<<dim3(8, NC_, 2), 256, 0, stream>>>(bt, gam, carry);
    norm_kernel<<<dim3(M_), 256, 0, stream>>>(bt, q, ogp, bog, mnw, mnb, gnw, gnb, gated, rnn);
    gemm_out_kernel<<<dim3(16, 16), 512, 98304, stream>>>(gated, W6, out);
}